// Round 1
// baseline (5793.831 us; speedup 1.0000x reference)
//
#include <hip/hip_runtime.h>
#include <hip/hip_bf16.h>
#include <math.h>

#define B_   8
#define N_   1024
#define D_   512
#define H_   8
#define HD_  64
#define D3_  1536
#define M_   (B_ * N_)   // 8192 tokens

static __device__ __forceinline__ float gelu_f(float x) {
    return 0.5f * x * (1.0f + erff(x * 0.7071067811865475f));
}

// block-wide sum, blockDim.x == 256 (4 waves)
static __device__ __forceinline__ float blk_sum(float v, float* red) {
    #pragma unroll
    for (int off = 32; off; off >>= 1) v += __shfl_xor(v, off);
    const int w = threadIdx.x >> 6;
    __syncthreads();                    // protect red[] reuse across calls
    if ((threadIdx.x & 63) == 0) red[w] = v;
    __syncthreads();
    return red[0] + red[1] + red[2] + red[3];
}

// ---------------------------------------------------------------------------
// Generic tiled f32 GEMM: C[M,N] = epi(A[M,K] (+A2) @ W[K,N] + bias)
// 64x64 tile, BK=16, 256 threads, 4x4 micro-tile per thread.
// ACT: 0 none, 1 exact-GELU.  SUMA: A_eff = A + A2.
// FINAL: C = fused + alpha*(acc+bias) + 0.5*beta*(r1+r2)
// ---------------------------------------------------------------------------
template <int ACT, bool SUMA, bool FINAL>
__global__ __launch_bounds__(256) void gemm_k(
    const float* __restrict__ A, const float* __restrict__ A2,
    const float* __restrict__ W, const float* __restrict__ bias,
    float* __restrict__ C, int M, int Nn, int K,
    const float* __restrict__ fusedp, const float* __restrict__ r1,
    const float* __restrict__ r2, const float* __restrict__ alphap,
    const float* __restrict__ betap)
{
    __shared__ float As[16][64];   // [k][m]
    __shared__ float Bs[16][64];   // [k][n]
    const int tid = threadIdx.x;
    const int tx = tid & 15, ty = tid >> 4;
    const int n0 = blockIdx.x * 64, m0 = blockIdx.y * 64;
    const int ai = tid >> 2, ak = (tid & 3) * 4;   // A-tile load coords
    const int wk = tid >> 4, wj = (tid & 15) * 4;  // W-tile load coords

    float acc[4][4] = {};
    for (int k0 = 0; k0 < K; k0 += 16) {
        __syncthreads();
        float4 av = *reinterpret_cast<const float4*>(&A[(size_t)(m0 + ai) * K + k0 + ak]);
        if (SUMA) {
            float4 a2 = *reinterpret_cast<const float4*>(&A2[(size_t)(m0 + ai) * K + k0 + ak]);
            av.x += a2.x; av.y += a2.y; av.z += a2.z; av.w += a2.w;
        }
        As[ak + 0][ai] = av.x; As[ak + 1][ai] = av.y;
        As[ak + 2][ai] = av.z; As[ak + 3][ai] = av.w;
        *reinterpret_cast<float4*>(&Bs[wk][wj]) =
            *reinterpret_cast<const float4*>(&W[(size_t)(k0 + wk) * Nn + n0 + wj]);
        __syncthreads();
        #pragma unroll
        for (int kk = 0; kk < 16; ++kk) {
            const float4 a = *reinterpret_cast<const float4*>(&As[kk][ty * 4]);
            const float4 b = *reinterpret_cast<const float4*>(&Bs[kk][tx * 4]);
            const float aa[4] = {a.x, a.y, a.z, a.w};
            const float bb[4] = {b.x, b.y, b.z, b.w};
            #pragma unroll
            for (int i = 0; i < 4; ++i)
                #pragma unroll
                for (int j = 0; j < 4; ++j) acc[i][j] += aa[i] * bb[j];
        }
    }

    float alpha = 0.f, beta = 0.f;
    if (FINAL) { alpha = alphap[0]; beta = betap[0]; }
    #pragma unroll
    for (int i = 0; i < 4; ++i) {
        const int m = m0 + ty * 4 + i;
        float4 o;
        float* op = &o.x;
        #pragma unroll
        for (int j = 0; j < 4; ++j) {
            const int n = n0 + tx * 4 + j;
            float v = acc[i][j] + bias[n];
            if (ACT == 1) v = gelu_f(v);
            if (FINAL) {
                const size_t idx = (size_t)m * Nn + n;
                v = fusedp[idx] + alpha * v + 0.5f * beta * (r1[idx] + r2[idx]);
            }
            op[j] = v;
        }
        *reinterpret_cast<float4*>(&C[(size_t)m * Nn + n0 + tx * 4]) = o;
    }
}

// ---------------------------------------------------------------------------
// In-place row LayerNorm: one 256-thread block per row of length `dim`.
// ---------------------------------------------------------------------------
__global__ __launch_bounds__(256) void ln_k(float* __restrict__ x,
                                            const float* __restrict__ g,
                                            const float* __restrict__ b,
                                            int dim, float inv_dim)
{
    __shared__ float red[4];
    float* xr = x + (size_t)blockIdx.x * dim;
    float s = 0.f, ss = 0.f;
    for (int j = threadIdx.x; j < dim; j += 256) {
        const float v = xr[j];
        s += v; ss += v * v;
    }
    s = blk_sum(s, red);
    ss = blk_sum(ss, red);
    const float mu = s * inv_dim;
    const float var = ss * inv_dim - mu * mu;
    const float rs = rsqrtf(var + 1e-5f);
    for (int j = threadIdx.x; j < dim; j += 256)
        xr[j] = (xr[j] - mu) * rs * g[j] + b[j];
}

// ---------------------------------------------------------------------------
// In-place l2-normalize each 64-elem head-row of q and k inside qkv buffer.
// One wave per row; grid = B*N*16/4 blocks of 256.
// ---------------------------------------------------------------------------
__global__ __launch_bounds__(256) void l2n_k(float* __restrict__ qkv)
{
    const int r = blockIdx.x * 4 + (threadIdx.x >> 6);
    const int lane = threadIdx.x & 63;
    const int bn = r >> 4;        // token index in [0, B*N)
    const int rem = r & 15;
    const int t = rem >> 3;       // 0 = q, 1 = k
    const int h = rem & 7;
    float* p = qkv + (size_t)bn * D3_ + t * D_ + h * HD_;
    const float v = p[lane];
    float s = v * v;
    #pragma unroll
    for (int off = 32; off; off >>= 1) s += __shfl_xor(s, off);
    const float nrm = sqrtf(s);
    p[lane] = v / fmaxf(nrm, 1e-12f);
}

// ---------------------------------------------------------------------------
// Cosine attention: one block per (b, h, 8-row tile). q in registers,
// K streamed from global (L1/L2), scores+softmax in LDS, V LDS-staged.
// out written head-concat: out[(b*N+n)*D + h*64 + d]
// ---------------------------------------------------------------------------
__global__ __launch_bounds__(256) void attn_k(const float* __restrict__ qkv,
                                              const float* __restrict__ temp,
                                              float* __restrict__ out)
{
    __shared__ float sc[8][1024];      // 32 KB score tile
    __shared__ float kv[64][68];       // padded V tile (17 KB)
    __shared__ float red[2][8][64];    // PV half-reduction
    __shared__ float den[8];
    const int tid = threadIdx.x;
    const int blk = blockIdx.x;
    const int nb = blk & 127;
    const int h  = (blk >> 7) & 7;
    const int b  = blk >> 10;
    const int n0 = nb * 8;
    const float t = temp[h];
    const size_t bb = (size_t)b * N_ * D3_;

    // ---- scores: thread (r = tid>>5, mi = tid&31) -> rows of sc
    {
        const int r = tid >> 5;
        const int mi = tid & 31;
        float4 qv[16];
        const float* qp = qkv + bb + (size_t)(n0 + r) * D3_ + h * HD_;
        #pragma unroll
        for (int u = 0; u < 16; ++u) qv[u] = reinterpret_cast<const float4*>(qp)[u];
        for (int m0 = 0; m0 < N_; m0 += 64) {
            #pragma unroll
            for (int e = 0; e < 2; ++e) {
                const int m = m0 + mi * 2 + e;
                const float* kp = qkv + bb + (size_t)m * D3_ + D_ + h * HD_;
                float acc = 0.f;
                #pragma unroll
                for (int u = 0; u < 16; ++u) {
                    const float4 k4 = reinterpret_cast<const float4*>(kp)[u];
                    acc += qv[u].x * k4.x + qv[u].y * k4.y +
                           qv[u].z * k4.z + qv[u].w * k4.w;
                }
                sc[r][m] = acc * t;
            }
        }
    }
    __syncthreads();

    // ---- softmax: wave w handles rows 2w, 2w+1
    {
        const int w = tid >> 6, lane = tid & 63;
        for (int rr = w * 2; rr < w * 2 + 2; ++rr) {
            float mx = -1e30f;
            for (int j = lane; j < N_; j += 64) mx = fmaxf(mx, sc[rr][j]);
            #pragma unroll
            for (int off = 32; off; off >>= 1) mx = fmaxf(mx, __shfl_xor(mx, off));
            float s = 0.f;
            for (int j = lane; j < N_; j += 64) {
                const float e = expf(sc[rr][j] - mx);
                sc[rr][j] = e;
                s += e;
            }
            #pragma unroll
            for (int off = 32; off; off >>= 1) s += __shfl_xor(s, off);
            if (lane == 0) den[rr] = 1.0f / s;
        }
    }
    __syncthreads();

    // ---- PV: thread (half = tid>>7, r = (tid>>4)&7, dq = tid&15)
    const int half = tid >> 7;
    const int r = (tid >> 4) & 7;
    const int dq = tid & 15;
    float4 acc = {0.f, 0.f, 0.f, 0.f};
    for (int m0 = 0; m0 < N_; m0 += 64) {
        __syncthreads();   // previous tile consumed
        for (int idx = tid; idx < 64 * 16; idx += 256) {
            const int mm = idx >> 4, dd = (idx & 15) * 4;
            const float4 v4 = *reinterpret_cast<const float4*>(
                qkv + bb + (size_t)(m0 + mm) * D3_ + 2 * D_ + h * HD_ + dd);
            *reinterpret_cast<float4*>(&kv[mm][dd]) = v4;
        }
        __syncthreads();
        const int mbase = half * 32;
        #pragma unroll
        for (int mm = 0; mm < 32; ++mm) {
            const float p = sc[r][m0 + mbase + mm];
            const float4 v = *reinterpret_cast<const float4*>(&kv[mbase + mm][dq * 4]);
            acc.x += p * v.x; acc.y += p * v.y;
            acc.z += p * v.z; acc.w += p * v.w;
        }
    }
    *reinterpret_cast<float4*>(&red[half][r][dq * 4]) = acc;
    __syncthreads();
    if (half == 0) {
        const float4 o2 = *reinterpret_cast<const float4*>(&red[1][r][dq * 4]);
        const float inv = den[r];
        float4 o;
        o.x = (acc.x + o2.x) * inv;
        o.y = (acc.y + o2.y) * inv;
        o.z = (acc.z + o2.z) * inv;
        o.w = (acc.w + o2.w) * inv;
        *reinterpret_cast<float4*>(out + (size_t)(b * N_ + n0 + r) * D_ + h * HD_ + dq * 4) = o;
    }
}

// ---------------------------------------------------------------------------
// Partial column sums for the gate means. grid = B*8, Gp[(b*8+c)*1024 + {d | 512+d}]
// ---------------------------------------------------------------------------
__global__ __launch_bounds__(256) void means_k(const float* __restrict__ spec,
                                               const float* __restrict__ spat,
                                               float* __restrict__ Gp)
{
    const int b = blockIdx.x >> 3;
    const int ch = blockIdx.x & 7;
    const int n0 = ch * 128;
    for (int d = threadIdx.x; d < D_; d += 256) {
        float s1 = 0.f, s2 = 0.f;
        for (int n = 0; n < 128; ++n) {
            const size_t idx = ((size_t)(b * N_) + n0 + n) * D_ + d;
            s1 += spec[idx];
            s2 += spat[idx];
        }
        Gp[(size_t)blockIdx.x * 1024 + d] = s1;
        Gp[(size_t)blockIdx.x * 1024 + 512 + d] = s2;
    }
}

// ---------------------------------------------------------------------------
// Gate MLP: concat-means -> Linear(1024,512) -> LN -> GELU -> Linear(512,3) -> softmax
// grid = B blocks.
// ---------------------------------------------------------------------------
__global__ __launch_bounds__(256) void gate_k(
    const float* __restrict__ Gp, const float* __restrict__ w1,
    const float* __restrict__ b1, const float* __restrict__ lng,
    const float* __restrict__ lnb, const float* __restrict__ w2,
    const float* __restrict__ b2, float* __restrict__ gate)
{
    __shared__ float xs[1024];
    __shared__ float red[4];
    const int b = blockIdx.x, tid = threadIdx.x;
    for (int j = tid; j < 1024; j += 256) {
        float s = 0.f;
        for (int c = 0; c < 8; ++c) s += Gp[(size_t)(b * 8 + c) * 1024 + j];
        xs[j] = s * (1.0f / N_);
    }
    __syncthreads();
    float y[2];
    #pragma unroll
    for (int u = 0; u < 2; ++u) {
        const int jj = tid + u * 256;
        float acc = b1[jj];
        for (int k = 0; k < 1024; ++k) acc += xs[k] * w1[(size_t)k * 512 + jj];
        y[u] = acc;
    }
    const float s = blk_sum(y[0] + y[1], red);
    const float ss = blk_sum(y[0] * y[0] + y[1] * y[1], red);
    const float mu = s * (1.0f / 512.0f);
    const float var = ss * (1.0f / 512.0f) - mu * mu;
    const float rs = rsqrtf(var + 1e-5f);
    float p0 = 0.f, p1 = 0.f, p2 = 0.f;
    #pragma unroll
    for (int u = 0; u < 2; ++u) {
        const int jj = tid + u * 256;
        const float z = gelu_f((y[u] - mu) * rs * lng[jj] + lnb[jj]);
        p0 += z * w2[jj * 3 + 0];
        p1 += z * w2[jj * 3 + 1];
        p2 += z * w2[jj * 3 + 2];
    }
    p0 = blk_sum(p0, red);
    p1 = blk_sum(p1, red);
    p2 = blk_sum(p2, red);
    if (tid == 0) {
        p0 += b2[0]; p1 += b2[1]; p2 += b2[2];
        const float m = fmaxf(p0, fmaxf(p1, p2));
        const float e0 = expf(p0 - m), e1 = expf(p1 - m), e2 = expf(p2 - m);
        const float inv = 1.0f / (e0 + e1 + e2);
        gate[b * 3 + 0] = e0 * inv;
        gate[b * 3 + 1] = e1 * inv;
        gate[b * 3 + 2] = e2 * inv;
    }
}

// ---------------------------------------------------------------------------
// fused = g0*spec + g1*spat + g2*vol  (float4 elementwise)
// ---------------------------------------------------------------------------
__global__ __launch_bounds__(256) void fuse_k(
    const float* __restrict__ spec, const float* __restrict__ spat,
    const float* __restrict__ vol, const float* __restrict__ gate,
    float* __restrict__ fused)
{
    const size_t i4 = ((size_t)blockIdx.x * 256 + threadIdx.x) * 4;
    const int b = (int)(i4 >> 19);   // / (N_*D_) = 524288
    const float g0 = gate[b * 3 + 0], g1 = gate[b * 3 + 1], g2 = gate[b * 3 + 2];
    const float4 a = *reinterpret_cast<const float4*>(spec + i4);
    const float4 c = *reinterpret_cast<const float4*>(spat + i4);
    const float4 v = *reinterpret_cast<const float4*>(vol + i4);
    float4 o;
    o.x = g0 * a.x + g1 * c.x + g2 * v.x;
    o.y = g0 * a.y + g1 * c.y + g2 * v.y;
    o.z = g0 * a.z + g1 * c.z + g2 * v.z;
    o.w = g0 * a.w + g1 * c.w + g2 * v.w;
    *reinterpret_cast<float4*>(fused + i4) = o;
}

// ---------------------------------------------------------------------------
extern "C" void kernel_launch(void* const* d_in, const int* in_sizes, int n_in,
                              void* d_out, int out_size, void* d_ws, size_t ws_size,
                              hipStream_t stream)
{
    const float* hsi    = (const float*)d_in[0];
    const float* lidar  = (const float*)d_in[1];
    const float* temp   = (const float*)d_in[2];
    const float* sq_w   = (const float*)d_in[3];
    const float* sq_b   = (const float*)d_in[4];
    const float* sq_lng = (const float*)d_in[5];
    const float* sq_lnb = (const float*)d_in[6];
    const float* sproj_w = (const float*)d_in[7];
    const float* sproj_b = (const float*)d_in[8];
    const float* pq_w   = (const float*)d_in[9];
    const float* pq_b   = (const float*)d_in[10];
    const float* pq_lng = (const float*)d_in[11];
    const float* pq_lnb = (const float*)d_in[12];
    const float* pproj_w = (const float*)d_in[13];
    const float* pproj_b = (const float*)d_in[14];
    const float* vf_w1  = (const float*)d_in[15];
    const float* vf_b1  = (const float*)d_in[16];
    const float* vf_w2  = (const float*)d_in[17];
    const float* vf_b2  = (const float*)d_in[18];
    const float* ag_w1  = (const float*)d_in[19];
    const float* ag_b1  = (const float*)d_in[20];
    const float* ag_lng = (const float*)d_in[21];
    const float* ag_lnb = (const float*)d_in[22];
    const float* ag_w2  = (const float*)d_in[23];
    const float* ag_b2  = (const float*)d_in[24];
    const float* fr_w1  = (const float*)d_in[25];
    const float* fr_b1  = (const float*)d_in[26];
    const float* fr_w2  = (const float*)d_in[27];
    const float* fr_b2  = (const float*)d_in[28];
    const float* alpha  = (const float*)d_in[29];
    const float* beta   = (const float*)d_in[30];
    float* out = (float*)d_out;

    // workspace layout (floats): total ~29.43M floats = ~118 MB
    float* wsA  = (float*)d_ws;                    // [8192,1536] qkv / MLP hidden
    float* wsB  = wsA + (size_t)M_ * D3_;          // [8192,512]  attn_out / volumetric
    float* wsC  = wsB + (size_t)M_ * D_;           // [8192,512]  out_spectral
    float* wsD  = wsC + (size_t)M_ * D_;           // [8192,512]  out_spatial
    float* wsE  = wsD + (size_t)M_ * D_;           // [8192,512]  fused
    float* Gp   = wsE + (size_t)M_ * D_;           // [64,1024] partial means
    float* gate = Gp + 64 * 1024;                  // [8,3]

    const dim3 blk(256);
    const dim3 g_qkv(D3_ / 64, M_ / 64);
    const dim3 g_d(D_ / 64, M_ / 64);
    const dim3 g_2d(1024 / 64, M_ / 64);

    // ---- spectral branch
    gemm_k<0, false, false><<<g_qkv, blk, 0, stream>>>(hsi, nullptr, sq_w, sq_b, wsA,
        M_, D3_, D_, nullptr, nullptr, nullptr, nullptr, nullptr);
    ln_k<<<M_, blk, 0, stream>>>(wsA, sq_lng, sq_lnb, D3_, 1.0f / D3_);
    l2n_k<<<M_ * 16 / 4, blk, 0, stream>>>(wsA);
    attn_k<<<B_ * H_ * (N_ / 8), blk, 0, stream>>>(wsA, temp, wsB);
    gemm_k<0, false, false><<<g_d, blk, 0, stream>>>(wsB, nullptr, sproj_w, sproj_b, wsC,
        M_, D_, D_, nullptr, nullptr, nullptr, nullptr, nullptr);

    // ---- spatial branch
    gemm_k<0, false, false><<<g_qkv, blk, 0, stream>>>(lidar, nullptr, pq_w, pq_b, wsA,
        M_, D3_, D_, nullptr, nullptr, nullptr, nullptr, nullptr);
    ln_k<<<M_, blk, 0, stream>>>(wsA, pq_lng, pq_lnb, D3_, 1.0f / D3_);
    l2n_k<<<M_ * 16 / 4, blk, 0, stream>>>(wsA);
    attn_k<<<B_ * H_ * (N_ / 8), blk, 0, stream>>>(wsA, temp, wsB);
    gemm_k<0, false, false><<<g_d, blk, 0, stream>>>(wsB, nullptr, pproj_w, pproj_b, wsD,
        M_, D_, D_, nullptr, nullptr, nullptr, nullptr, nullptr);

    // ---- volumetric MLP: hidden = gelu((spec+spat)@vf_w1+b1); vol = hidden@vf_w2+b2
    gemm_k<1, true, false><<<g_2d, blk, 0, stream>>>(wsC, wsD, vf_w1, vf_b1, wsA,
        M_, 1024, D_, nullptr, nullptr, nullptr, nullptr, nullptr);
    gemm_k<0, false, false><<<g_d, blk, 0, stream>>>(wsA, nullptr, vf_w2, vf_b2, wsB,
        M_, D_, 1024, nullptr, nullptr, nullptr, nullptr, nullptr);

    // ---- adaptive gate
    means_k<<<B_ * 8, blk, 0, stream>>>(wsC, wsD, Gp);
    gate_k<<<B_, blk, 0, stream>>>(Gp, ag_w1, ag_b1, ag_lng, ag_lnb, ag_w2, ag_b2, gate);
    fuse_k<<<M_ * D_ / 4 / 256, blk, 0, stream>>>(wsC, wsD, wsB, gate, wsE);

    // ---- fused recal MLP + final combine (epilogue)
    gemm_k<1, false, false><<<g_2d, blk, 0, stream>>>(wsE, nullptr, fr_w1, fr_b1, wsA,
        M_, 1024, D_, nullptr, nullptr, nullptr, nullptr, nullptr);
    gemm_k<0, false, true><<<g_d, blk, 0, stream>>>(wsA, nullptr, fr_w2, fr_b2, out,
        M_, D_, 1024, wsE, hsi, lidar, alpha, beta);
}

// Round 2
// 1199.029 us; speedup vs baseline: 4.8321x; 4.8321x over previous
//
#include <hip/hip_runtime.h>
#include <hip/hip_bf16.h>
#include <math.h>

#define B_   8
#define N_   1024
#define D_   512
#define H_   8
#define HD_  64
#define D3_  1536
#define M_   (B_ * N_)   // 8192 tokens

typedef float f32x4 __attribute__((ext_vector_type(4)));
typedef __bf16 bf16x8 __attribute__((ext_vector_type(8)));

union FragU {
    uint4 u4;
    unsigned int u[4];
    ushort s[8];
    bf16x8 v;
};

static __device__ __forceinline__ ushort f2bf(float x) {
    union { __bf16 h; ushort u; } c;
    c.h = (__bf16)x;
    return c.u;
}

static __device__ __forceinline__ unsigned int pack2(float a, float b) {
    return (unsigned int)f2bf(a) | ((unsigned int)f2bf(b) << 16);
}

static __device__ __forceinline__ float gelu_f(float x) {
    return 0.5f * x * (1.0f + erff(x * 0.7071067811865475f));
}

// block-wide sum, blockDim.x == 256 (4 waves)
static __device__ __forceinline__ float blk_sum(float v, float* red) {
    #pragma unroll
    for (int off = 32; off; off >>= 1) v += __shfl_xor(v, off);
    const int w = threadIdx.x >> 6;
    __syncthreads();
    if ((threadIdx.x & 63) == 0) red[w] = v;
    __syncthreads();
    return red[0] + red[1] + red[2] + red[3];
}

// ---------------------------------------------------------------------------
// Generic tiled f32 GEMM (unchanged from round 1)
// ---------------------------------------------------------------------------
template <int ACT, bool SUMA, bool FINAL>
__global__ __launch_bounds__(256) void gemm_k(
    const float* __restrict__ A, const float* __restrict__ A2,
    const float* __restrict__ W, const float* __restrict__ bias,
    float* __restrict__ C, int M, int Nn, int K,
    const float* __restrict__ fusedp, const float* __restrict__ r1,
    const float* __restrict__ r2, const float* __restrict__ alphap,
    const float* __restrict__ betap)
{
    __shared__ float As[16][64];
    __shared__ float Bs[16][64];
    const int tid = threadIdx.x;
    const int tx = tid & 15, ty = tid >> 4;
    const int n0 = blockIdx.x * 64, m0 = blockIdx.y * 64;
    const int ai = tid >> 2, ak = (tid & 3) * 4;
    const int wk = tid >> 4, wj = (tid & 15) * 4;

    float acc[4][4] = {};
    for (int k0 = 0; k0 < K; k0 += 16) {
        __syncthreads();
        float4 av = *reinterpret_cast<const float4*>(&A[(size_t)(m0 + ai) * K + k0 + ak]);
        if (SUMA) {
            float4 a2 = *reinterpret_cast<const float4*>(&A2[(size_t)(m0 + ai) * K + k0 + ak]);
            av.x += a2.x; av.y += a2.y; av.z += a2.z; av.w += a2.w;
        }
        As[ak + 0][ai] = av.x; As[ak + 1][ai] = av.y;
        As[ak + 2][ai] = av.z; As[ak + 3][ai] = av.w;
        *reinterpret_cast<float4*>(&Bs[wk][wj]) =
            *reinterpret_cast<const float4*>(&W[(size_t)(k0 + wk) * Nn + n0 + wj]);
        __syncthreads();
        #pragma unroll
        for (int kk = 0; kk < 16; ++kk) {
            const float4 a = *reinterpret_cast<const float4*>(&As[kk][ty * 4]);
            const float4 b = *reinterpret_cast<const float4*>(&Bs[kk][tx * 4]);
            const float aa[4] = {a.x, a.y, a.z, a.w};
            const float bb[4] = {b.x, b.y, b.z, b.w};
            #pragma unroll
            for (int i = 0; i < 4; ++i)
                #pragma unroll
                for (int j = 0; j < 4; ++j) acc[i][j] += aa[i] * bb[j];
        }
    }

    float alpha = 0.f, beta = 0.f;
    if (FINAL) { alpha = alphap[0]; beta = betap[0]; }
    #pragma unroll
    for (int i = 0; i < 4; ++i) {
        const int m = m0 + ty * 4 + i;
        float4 o;
        float* op = &o.x;
        #pragma unroll
        for (int j = 0; j < 4; ++j) {
            const int n = n0 + tx * 4 + j;
            float v = acc[i][j] + bias[n];
            if (ACT == 1) v = gelu_f(v);
            if (FINAL) {
                const size_t idx = (size_t)m * Nn + n;
                v = fusedp[idx] + alpha * v + 0.5f * beta * (r1[idx] + r2[idx]);
            }
            op[j] = v;
        }
        *reinterpret_cast<float4*>(&C[(size_t)m * Nn + n0 + tx * 4]) = o;
    }
}

// ---------------------------------------------------------------------------
// In-place row LayerNorm (unchanged)
// ---------------------------------------------------------------------------
__global__ __launch_bounds__(256) void ln_k(float* __restrict__ x,
                                            const float* __restrict__ g,
                                            const float* __restrict__ b,
                                            int dim, float inv_dim)
{
    __shared__ float red[4];
    float* xr = x + (size_t)blockIdx.x * dim;
    float s = 0.f, ss = 0.f;
    for (int j = threadIdx.x; j < dim; j += 256) {
        const float v = xr[j];
        s += v; ss += v * v;
    }
    s = blk_sum(s, red);
    ss = blk_sum(ss, red);
    const float mu = s * inv_dim;
    const float var = ss * inv_dim - mu * mu;
    const float rs = rsqrtf(var + 1e-5f);
    for (int j = threadIdx.x; j < dim; j += 256)
        xr[j] = (xr[j] - mu) * rs * g[j] + b[j];
}

// ---------------------------------------------------------------------------
// prep: l2norm K -> bf16 Kb[bh][n][64]; V -> bf16 transposed Vt[bh][d][1024]
// grid = B*H*16 blocks of 256 (one per 64-token tile).
// ---------------------------------------------------------------------------
__global__ __launch_bounds__(256) void prep_k(const float* __restrict__ qkv,
                                              ushort* __restrict__ Kb,
                                              ushort* __restrict__ Vt)
{
    __shared__ ushort Vs[64 * 72];
    const int nb = blockIdx.x & 15;
    const int h  = (blockIdx.x >> 4) & 7;
    const int b  = blockIdx.x >> 7;
    const int bh = b * 8 + h;
    const int n0 = nb * 64;
    const int w = threadIdx.x >> 6;
    const int l = threadIdx.x & 63;

    #pragma unroll 4
    for (int i = 0; i < 16; ++i) {
        const int row = w * 16 + i;
        const float* base = qkv + ((size_t)(b * N_) + n0 + row) * D3_ + h * HD_;
        const float kvl = base[D_ + l];
        const float vvl = base[2 * D_ + l];
        float ssq = kvl * kvl;
        #pragma unroll
        for (int off = 32; off; off >>= 1) ssq += __shfl_xor(ssq, off);
        const float sc = 1.0f / fmaxf(sqrtf(ssq), 1e-12f);
        Kb[((size_t)bh * N_ + n0 + row) * HD_ + l] = f2bf(kvl * sc);
        Vs[row * 72 + l] = f2bf(vvl);
    }
    __syncthreads();
    // transposed V write: thread t -> d = t>>2, seg = t&3 (16 keys each)
    const int d = threadIdx.x >> 2, seg = threadIdx.x & 3;
    ushort tmp[16];
    #pragma unroll
    for (int i = 0; i < 16; ++i) tmp[i] = Vs[(seg * 16 + i) * 72 + d];
    ushort* dst = Vt + ((size_t)bh * HD_ + d) * N_ + n0 + seg * 16;
    *reinterpret_cast<uint4*>(dst)     = *reinterpret_cast<uint4*>(&tmp[0]);
    *reinterpret_cast<uint4*>(dst + 8) = *reinterpret_cast<uint4*>(&tmp[8]);
}

// ---------------------------------------------------------------------------
// Flash-style cosine attention, bf16 MFMA (16x16x32), swapped QK^T.
// Block = 256 thr (4 waves), QBLK=64 (16 q-rows/wave), KVBLK=64, 16 kv tiles.
// Q read f32 from qkv, l2normed in-register, temperature folded in.
// Static softmax shift m = |t| (scores bounded by |t| since q,k unit vectors).
// out[(b*N+n)*512 + h*64 + d]  (f32)
// ---------------------------------------------------------------------------
__global__ __launch_bounds__(256) void fattn_k(const float* __restrict__ qkv,
                                               const ushort* __restrict__ Kb,
                                               const ushort* __restrict__ Vt,
                                               const float* __restrict__ temp,
                                               float* __restrict__ out)
{
    __shared__ ushort Ks[64 * 72];
    __shared__ ushort Vs[64 * 72];
    const int tid = threadIdx.x;
    const int nb = blockIdx.x & 15;
    const int h  = (blockIdx.x >> 4) & 7;
    const int b  = blockIdx.x >> 7;
    const int bh = b * 8 + h;
    const int n0 = nb * 64;
    const int w  = tid >> 6;
    const int l  = tid & 63;
    const int lr = l & 15;     // 16-row/col index
    const int g  = l >> 4;     // lane group
    const float t = temp[h];
    const float mabs = fabsf(t);

    // ---- Q fragment: f32 load, l2norm (full 64-dim row), *t, -> bf16
    const float* qrow = qkv + ((size_t)(b * N_) + n0 + w * 16 + lr) * D3_ + h * HD_;
    float qv[16];
    {
        const float4 q0 = *reinterpret_cast<const float4*>(qrow + 8 * g);
        const float4 q1 = *reinterpret_cast<const float4*>(qrow + 8 * g + 4);
        const float4 q2 = *reinterpret_cast<const float4*>(qrow + 32 + 8 * g);
        const float4 q3 = *reinterpret_cast<const float4*>(qrow + 32 + 8 * g + 4);
        qv[0]=q0.x; qv[1]=q0.y; qv[2]=q0.z; qv[3]=q0.w;
        qv[4]=q1.x; qv[5]=q1.y; qv[6]=q1.z; qv[7]=q1.w;
        qv[8]=q2.x; qv[9]=q2.y; qv[10]=q2.z; qv[11]=q2.w;
        qv[12]=q3.x; qv[13]=q3.y; qv[14]=q3.z; qv[15]=q3.w;
    }
    float ssq = 0.f;
    #pragma unroll
    for (int e = 0; e < 16; ++e) ssq += qv[e] * qv[e];
    ssq += __shfl_xor(ssq, 16);
    ssq += __shfl_xor(ssq, 32);
    const float qscale = t / fmaxf(sqrtf(ssq), 1e-12f);
    FragU qf0, qf1;
    #pragma unroll
    for (int e = 0; e < 8; ++e) {
        qf0.s[e] = f2bf(qv[e] * qscale);
        qf1.s[e] = f2bf(qv[8 + e] * qscale);
    }

    f32x4 O0 = {0.f,0.f,0.f,0.f}, O1 = {0.f,0.f,0.f,0.f};
    f32x4 O2 = {0.f,0.f,0.f,0.f}, O3 = {0.f,0.f,0.f,0.f};
    float lsum = 0.f;

    const ushort* kbase = Kb + (size_t)bh * N_ * HD_;
    const ushort* vbase = Vt + (size_t)bh * HD_ * N_;

    for (int kt = 0; kt < 16; ++kt) {
        __syncthreads();
        // ---- stage K tile [64 keys][64 d] -> Ks[64][72], Vt tile -> Vs[64][72]
        {
            const ushort* ksrc = kbase + (size_t)(kt * 64) * HD_;
            const ushort* vsrc = vbase + kt * 64;
            #pragma unroll
            for (int i = 0; i < 2; ++i) {
                const int c = tid + i * 256;
                const int row = c >> 3, c8 = (c & 7) * 8;
                *reinterpret_cast<uint4*>(&Ks[row * 72 + c8]) =
                    *reinterpret_cast<const uint4*>(ksrc + row * HD_ + c8);
            }
            #pragma unroll
            for (int i = 0; i < 2; ++i) {
                const int c = tid + i * 256;
                const int d = c >> 3, c8 = (c & 7) * 8;
                *reinterpret_cast<uint4*>(&Vs[d * 72 + c8]) =
                    *reinterpret_cast<const uint4*>(vsrc + (size_t)d * N_ + c8);
            }
        }
        __syncthreads();

        // ---- S^T = K @ Q^T per 16-key subtile; p = exp(s - |t|)
        float p[4][4];
        #pragma unroll
        for (int j = 0; j < 4; ++j) {
            f32x4 s = {0.f,0.f,0.f,0.f};
            FragU ka, kc;
            ka.u4 = *reinterpret_cast<const uint4*>(&Ks[(j * 16 + lr) * 72 + 8 * g]);
            kc.u4 = *reinterpret_cast<const uint4*>(&Ks[(j * 16 + lr) * 72 + 32 + 8 * g]);
            s = __builtin_amdgcn_mfma_f32_16x16x32_bf16(ka.v, qf0.v, s, 0, 0, 0);
            s = __builtin_amdgcn_mfma_f32_16x16x32_bf16(kc.v, qf1.v, s, 0, 0, 0);
            #pragma unroll
            for (int r = 0; r < 4; ++r) {
                const float pv = __expf(s[r] - mabs);
                p[j][r] = pv;
                lsum += pv;
            }
        }

        // ---- PV: O[16 q][64 d] += P[16 q][64 keys] @ V[64 keys][64 d]
        #pragma unroll
        for (int ks = 0; ks < 2; ++ks) {
            FragU pa;
            pa.u[0] = pack2(p[2 * ks][0],     p[2 * ks][1]);
            pa.u[1] = pack2(p[2 * ks][2],     p[2 * ks][3]);
            pa.u[2] = pack2(p[2 * ks + 1][0], p[2 * ks + 1][1]);
            pa.u[3] = pack2(p[2 * ks + 1][2], p[2 * ks + 1][3]);
            #pragma unroll
            for (int s4 = 0; s4 < 4; ++s4) {
                FragU vb;
                const int vi = (lr + 16 * s4) * 72 + ks * 32 + 4 * g;
                *reinterpret_cast<uint2*>(&vb.u[0]) =
                    *reinterpret_cast<const uint2*>(&Vs[vi]);
                *reinterpret_cast<uint2*>(&vb.u[2]) =
                    *reinterpret_cast<const uint2*>(&Vs[vi + 16]);
                f32x4& Oc = (s4 == 0) ? O0 : (s4 == 1) ? O1 : (s4 == 2) ? O2 : O3;
                Oc = __builtin_amdgcn_mfma_f32_16x16x32_bf16(pa.v, vb.v, Oc, 0, 0, 0);
            }
        }
    }

    // ---- normalize and store
    lsum += __shfl_xor(lsum, 16);
    lsum += __shfl_xor(lsum, 32);
    const float inv = 1.0f / lsum;
    float* outp = out + ((size_t)(b * N_) + n0 + w * 16) * D_ + h * HD_;
    #pragma unroll
    for (int r = 0; r < 4; ++r) {
        const float invr = __shfl(inv, 4 * g + r);
        float* orow = outp + (size_t)(4 * g + r) * D_;
        orow[0 * 16 + lr] = O0[r] * invr;
        orow[1 * 16 + lr] = O1[r] * invr;
        orow[2 * 16 + lr] = O2[r] * invr;
        orow[3 * 16 + lr] = O3[r] * invr;
    }
}

// ---------------------------------------------------------------------------
// Partial column sums for gate means (unchanged)
// ---------------------------------------------------------------------------
__global__ __launch_bounds__(256) void means_k(const float* __restrict__ spec,
                                               const float* __restrict__ spat,
                                               float* __restrict__ Gp)
{
    const int b = blockIdx.x >> 3;
    const int ch = blockIdx.x & 7;
    const int n0 = ch * 128;
    for (int d = threadIdx.x; d < D_; d += 256) {
        float s1 = 0.f, s2 = 0.f;
        for (int n = 0; n < 128; ++n) {
            const size_t idx = ((size_t)(b * N_) + n0 + n) * D_ + d;
            s1 += spec[idx];
            s2 += spat[idx];
        }
        Gp[(size_t)blockIdx.x * 1024 + d] = s1;
        Gp[(size_t)blockIdx.x * 1024 + 512 + d] = s2;
    }
}

// ---------------------------------------------------------------------------
// Gate MLP (unchanged)
// ---------------------------------------------------------------------------
__global__ __launch_bounds__(256) void gate_k(
    const float* __restrict__ Gp, const float* __restrict__ w1,
    const float* __restrict__ b1, const float* __restrict__ lng,
    const float* __restrict__ lnb, const float* __restrict__ w2,
    const float* __restrict__ b2, float* __restrict__ gate)
{
    __shared__ float xs[1024];
    __shared__ float red[4];
    const int b = blockIdx.x, tid = threadIdx.x;
    for (int j = tid; j < 1024; j += 256) {
        float s = 0.f;
        for (int c = 0; c < 8; ++c) s += Gp[(size_t)(b * 8 + c) * 1024 + j];
        xs[j] = s * (1.0f / N_);
    }
    __syncthreads();
    float y[2];
    #pragma unroll
    for (int u = 0; u < 2; ++u) {
        const int jj = tid + u * 256;
        float acc = b1[jj];
        for (int k = 0; k < 1024; ++k) acc += xs[k] * w1[(size_t)k * 512 + jj];
        y[u] = acc;
    }
    const float s = blk_sum(y[0] + y[1], red);
    const float ss = blk_sum(y[0] * y[0] + y[1] * y[1], red);
    const float mu = s * (1.0f / 512.0f);
    const float var = ss * (1.0f / 512.0f) - mu * mu;
    const float rs = rsqrtf(var + 1e-5f);
    float p0 = 0.f, p1 = 0.f, p2 = 0.f;
    #pragma unroll
    for (int u = 0; u < 2; ++u) {
        const int jj = tid + u * 256;
        const float z = gelu_f((y[u] - mu) * rs * lng[jj] + lnb[jj]);
        p0 += z * w2[jj * 3 + 0];
        p1 += z * w2[jj * 3 + 1];
        p2 += z * w2[jj * 3 + 2];
    }
    p0 = blk_sum(p0, red);
    p1 = blk_sum(p1, red);
    p2 = blk_sum(p2, red);
    if (tid == 0) {
        p0 += b2[0]; p1 += b2[1]; p2 += b2[2];
        const float m = fmaxf(p0, fmaxf(p1, p2));
        const float e0 = expf(p0 - m), e1 = expf(p1 - m), e2 = expf(p2 - m);
        const float inv = 1.0f / (e0 + e1 + e2);
        gate[b * 3 + 0] = e0 * inv;
        gate[b * 3 + 1] = e1 * inv;
        gate[b * 3 + 2] = e2 * inv;
    }
}

// ---------------------------------------------------------------------------
// fused = g0*spec + g1*spat + g2*vol (unchanged)
// ---------------------------------------------------------------------------
__global__ __launch_bounds__(256) void fuse_k(
    const float* __restrict__ spec, const float* __restrict__ spat,
    const float* __restrict__ vol, const float* __restrict__ gate,
    float* __restrict__ fused)
{
    const size_t i4 = ((size_t)blockIdx.x * 256 + threadIdx.x) * 4;
    const int b = (int)(i4 >> 19);
    const float g0 = gate[b * 3 + 0], g1 = gate[b * 3 + 1], g2 = gate[b * 3 + 2];
    const float4 a = *reinterpret_cast<const float4*>(spec + i4);
    const float4 c = *reinterpret_cast<const float4*>(spat + i4);
    const float4 v = *reinterpret_cast<const float4*>(vol + i4);
    float4 o;
    o.x = g0 * a.x + g1 * c.x + g2 * v.x;
    o.y = g0 * a.y + g1 * c.y + g2 * v.y;
    o.z = g0 * a.z + g1 * c.z + g2 * v.z;
    o.w = g0 * a.w + g1 * c.w + g2 * v.w;
    *reinterpret_cast<float4*>(fused + i4) = o;
}

// ---------------------------------------------------------------------------
extern "C" void kernel_launch(void* const* d_in, const int* in_sizes, int n_in,
                              void* d_out, int out_size, void* d_ws, size_t ws_size,
                              hipStream_t stream)
{
    const float* hsi    = (const float*)d_in[0];
    const float* lidar  = (const float*)d_in[1];
    const float* temp   = (const float*)d_in[2];
    const float* sq_w   = (const float*)d_in[3];
    const float* sq_b   = (const float*)d_in[4];
    const float* sq_lng = (const float*)d_in[5];
    const float* sq_lnb = (const float*)d_in[6];
    const float* sproj_w = (const float*)d_in[7];
    const float* sproj_b = (const float*)d_in[8];
    const float* pq_w   = (const float*)d_in[9];
    const float* pq_b   = (const float*)d_in[10];
    const float* pq_lng = (const float*)d_in[11];
    const float* pq_lnb = (const float*)d_in[12];
    const float* pproj_w = (const float*)d_in[13];
    const float* pproj_b = (const float*)d_in[14];
    const float* vf_w1  = (const float*)d_in[15];
    const float* vf_b1  = (const float*)d_in[16];
    const float* vf_w2  = (const float*)d_in[17];
    const float* vf_b2  = (const float*)d_in[18];
    const float* ag_w1  = (const float*)d_in[19];
    const float* ag_b1  = (const float*)d_in[20];
    const float* ag_lng = (const float*)d_in[21];
    const float* ag_lnb = (const float*)d_in[22];
    const float* ag_w2  = (const float*)d_in[23];
    const float* ag_b2  = (const float*)d_in[24];
    const float* fr_w1  = (const float*)d_in[25];
    const float* fr_b1  = (const float*)d_in[26];
    const float* fr_w2  = (const float*)d_in[27];
    const float* fr_b2  = (const float*)d_in[28];
    const float* alpha  = (const float*)d_in[29];
    const float* beta   = (const float*)d_in[30];
    float* out = (float*)d_out;

    float* wsA  = (float*)d_ws;                    // [8192,1536] qkv / MLP hidden
    float* wsB  = wsA + (size_t)M_ * D3_;          // [8192,512]  attn_out / volumetric
    float* wsC  = wsB + (size_t)M_ * D_;           // [8192,512]  out_spectral
    float* wsD  = wsC + (size_t)M_ * D_;           // [8192,512]  out_spatial
    float* wsE  = wsD + (size_t)M_ * D_;           // [8192,512]  fused  (aliases Kb/Vt)
    float* Gp   = wsE + (size_t)M_ * D_;           // [64,1024] partial means
    float* gate = Gp + 64 * 1024;                  // [8,3]

    // bf16 attention operands alias wsE (dead until fuse_k): 8.39 MB + 8.39 MB
    ushort* Kb = (ushort*)wsE;                          // [64][1024][64]
    ushort* Vt = Kb + (size_t)B_ * H_ * N_ * HD_;       // [64][64][1024]

    const dim3 blk(256);
    const dim3 g_qkv(D3_ / 64, M_ / 64);
    const dim3 g_d(D_ / 64, M_ / 64);
    const dim3 g_2d(1024 / 64, M_ / 64);
    const int g_attn = B_ * H_ * (N_ / 64);   // 1024

    // ---- spectral branch: qkv GEMM -> LN -> prep -> attn(wsB) -> proj(wsC)
    gemm_k<0, false, false><<<g_qkv, blk, 0, stream>>>(hsi, nullptr, sq_w, sq_b, wsA,
        M_, D3_, D_, nullptr, nullptr, nullptr, nullptr, nullptr);
    ln_k<<<M_, blk, 0, stream>>>(wsA, sq_lng, sq_lnb, D3_, 1.0f / D3_);
    prep_k<<<g_attn, blk, 0, stream>>>(wsA, Kb, Vt);
    fattn_k<<<g_attn, blk, 0, stream>>>(wsA, Kb, Vt, temp, wsB);
    gemm_k<0, false, false><<<g_d, blk, 0, stream>>>(wsB, nullptr, sproj_w, sproj_b, wsC,
        M_, D_, D_, nullptr, nullptr, nullptr, nullptr, nullptr);

    // ---- spatial branch: attn out goes through wsB again, proj -> wsD
    gemm_k<0, false, false><<<g_qkv, blk, 0, stream>>>(lidar, nullptr, pq_w, pq_b, wsA,
        M_, D3_, D_, nullptr, nullptr, nullptr, nullptr, nullptr);
    ln_k<<<M_, blk, 0, stream>>>(wsA, pq_lng, pq_lnb, D3_, 1.0f / D3_);
    prep_k<<<g_attn, blk, 0, stream>>>(wsA, Kb, Vt);
    fattn_k<<<g_attn, blk, 0, stream>>>(wsA, Kb, Vt, temp, wsB);
    gemm_k<0, false, false><<<g_d, blk, 0, stream>>>(wsB, nullptr, pproj_w, pproj_b, wsD,
        M_, D_, D_, nullptr, nullptr, nullptr, nullptr, nullptr);

    // ---- volumetric MLP: hidden = gelu((spec+spat)@vf_w1+b1); vol = hidden@vf_w2+b2
    gemm_k<1, true, false><<<g_2d, blk, 0, stream>>>(wsC, wsD, vf_w1, vf_b1, wsA,
        M_, 1024, D_, nullptr, nullptr, nullptr, nullptr, nullptr);
    gemm_k<0, false, false><<<g_d, blk, 0, stream>>>(wsA, nullptr, vf_w2, vf_b2, wsB,
        M_, D_, 1024, nullptr, nullptr, nullptr, nullptr, nullptr);

    // ---- adaptive gate
    means_k<<<B_ * 8, blk, 0, stream>>>(wsC, wsD, Gp);
    gate_k<<<B_, blk, 0, stream>>>(Gp, ag_w1, ag_b1, ag_lng, ag_lnb, ag_w2, ag_b2, gate);
    fuse_k<<<M_ * D_ / 4 / 256, blk, 0, stream>>>(wsC, wsD, wsB, gate, wsE);

    // ---- fused recal MLP + final combine (epilogue)
    gemm_k<1, false, false><<<g_2d, blk, 0, stream>>>(wsE, nullptr, fr_w1, fr_b1, wsA,
        M_, 1024, D_, nullptr, nullptr, nullptr, nullptr, nullptr);
    gemm_k<0, false, true><<<g_d, blk, 0, stream>>>(wsA, nullptr, fr_w2, fr_b2, out,
        M_, D_, 1024, wsE, hsi, lidar, alpha, beta);
}

// Round 3
// 487.405 us; speedup vs baseline: 11.8871x; 2.4600x over previous
//
#include <hip/hip_runtime.h>
#include <hip/hip_bf16.h>
#include <math.h>

#define B_   8
#define N_   1024
#define D_   512
#define H_   8
#define HD_  64
#define D3_  1536
#define M_   (B_ * N_)   // 8192 tokens

// bf16 weight-pool offsets (elements)
#define WOFF_SQ    0
#define WOFF_PQ    786432
#define WOFF_SPROJ 1572864
#define WOFF_PPROJ 1835008
#define WOFF_VF1   2097152
#define WOFF_VF2   2621440
#define WOFF_FR1   3145728
#define WOFF_FR2   3670016

typedef float f32x4 __attribute__((ext_vector_type(4)));
typedef __bf16 bf16x8 __attribute__((ext_vector_type(8)));

union FragU {
    uint4 u4;
    unsigned int u[4];
    ushort s[8];
    bf16x8 v;
};

static __device__ __forceinline__ ushort f2bf(float x) {
    union { __bf16 h; ushort u; } c;
    c.h = (__bf16)x;
    return c.u;
}

static __device__ __forceinline__ unsigned int pack2(float a, float b) {
    return (unsigned int)f2bf(a) | ((unsigned int)f2bf(b) << 16);
}

static __device__ __forceinline__ float gelu_f(float x) {
    return 0.5f * x * (1.0f + erff(x * 0.7071067811865475f));
}

// async global->LDS, 16B per lane; lds base must be wave-uniform
static __device__ __forceinline__ void gload16(const ushort* g, ushort* lds) {
    __builtin_amdgcn_global_load_lds(
        (const __attribute__((address_space(1))) void*)g,
        (__attribute__((address_space(3))) void*)lds, 16, 0, 0);
}

// block-wide sum, blockDim.x == 256 (4 waves)
static __device__ __forceinline__ float blk_sum(float v, float* red) {
    #pragma unroll
    for (int off = 32; off; off >>= 1) v += __shfl_xor(v, off);
    const int w = threadIdx.x >> 6;
    __syncthreads();
    if ((threadIdx.x & 63) == 0) red[w] = v;
    __syncthreads();
    return red[0] + red[1] + red[2] + red[3];
}

// ---------------------------------------------------------------------------
// bf16 MFMA GEMM: C[M,N] = epi(A[M,K] @ W[K,N] + bias),  W given as Wt[N][K].
// 128x128 tile, BK=32, 256 thr (4 waves, 2x2), 4x4 16x16 frags per wave.
// Fragment-major LDS (zero-conflict ds_read_b128), global_load_lds staging,
// 2-phase prefetch. OUT: 0=f32, 1=bf16. ACT: 0 none, 1 exact GELU.
// FINAL: C = fusedp + alpha*(acc+bias) + 0.5*beta*(r1+r2)
// ---------------------------------------------------------------------------
template <int ACT, int OUT, bool FINAL>
__global__ __launch_bounds__(256) void bgemm_k(
    const ushort* __restrict__ A, const ushort* __restrict__ Wt,
    const float* __restrict__ bias, void* __restrict__ Cv,
    int M, int Nn, int K,
    const float* __restrict__ fusedp, const float* __restrict__ r1,
    const float* __restrict__ r2, const float* __restrict__ alphap,
    const float* __restrict__ betap)
{
    __shared__ ushort Asm[2][4096];   // 8 KB per buffer: 8 chunks x 64 lanes x 8 bf16
    __shared__ ushort Bsm[2][4096];
    const int tid = threadIdx.x;
    const int w = tid >> 6, l = tid & 63;
    const int m0 = blockIdx.y * 128, n0 = blockIdx.x * 128;
    const int wr = w >> 1, wc = w & 1;
    const int lr = l & 15, g = l >> 4;

    // staging: chunk c -> rows (c>>2)*64 + (c&3)*16 + (l&15), k-chunk l>>4
    const int srow = (l & 15);
    const int skof = 8 * (l >> 4);

    f32x4 acc[4][4] = {};
    const int nt = K >> 5;

    // chunk row offsets for this wave's two chunks (c = 2w, 2w+1)
    const int c0 = 2 * w, c1 = 2 * w + 1;
    const int ar0 = (c0 >> 2) * 64 + (c0 & 3) * 16 + srow;
    const int ar1 = (c1 >> 2) * 64 + (c1 & 3) * 16 + srow;

    #define STAGE(buf, kt)                                                      \
        do {                                                                    \
            const int k0s = (kt) << 5;                                          \
            gload16(&A[(size_t)(m0 + ar0) * K + k0s + skof], &Asm[buf][c0*512]);\
            gload16(&A[(size_t)(m0 + ar1) * K + k0s + skof], &Asm[buf][c1*512]);\
            gload16(&Wt[(size_t)(n0 + ar0) * K + k0s + skof], &Bsm[buf][c0*512]);\
            gload16(&Wt[(size_t)(n0 + ar1) * K + k0s + skof], &Bsm[buf][c1*512]);\
        } while (0)

    STAGE(0, 0);
    __syncthreads();
    int cur = 0;
    for (int t = 0; t < nt; ++t) {
        if (t + 1 < nt) STAGE(cur ^ 1, t + 1);
        FragU af[4], bf4[4];
        #pragma unroll
        for (int mi = 0; mi < 4; ++mi)
            af[mi].u4 = *reinterpret_cast<const uint4*>(&Asm[cur][((wr*4 + mi)*64 + l)*8]);
        #pragma unroll
        for (int nj = 0; nj < 4; ++nj)
            bf4[nj].u4 = *reinterpret_cast<const uint4*>(&Bsm[cur][((wc*4 + nj)*64 + l)*8]);
        #pragma unroll
        for (int mi = 0; mi < 4; ++mi)
            #pragma unroll
            for (int nj = 0; nj < 4; ++nj)
                acc[mi][nj] = __builtin_amdgcn_mfma_f32_16x16x32_bf16(
                    af[mi].v, bf4[nj].v, acc[mi][nj], 0, 0, 0);
        __syncthreads();
        cur ^= 1;
    }
    #undef STAGE

    float alpha = 0.f, beta = 0.f;
    if (FINAL) { alpha = alphap[0]; beta = betap[0]; }
    // D layout: col = n-side lane&15, row = (lane>>4)*4 + reg
    #pragma unroll
    for (int mi = 0; mi < 4; ++mi) {
        #pragma unroll
        for (int r = 0; r < 4; ++r) {
            const int m = m0 + wr*64 + mi*16 + g*4 + r;
            #pragma unroll
            for (int nj = 0; nj < 4; ++nj) {
                const int n = n0 + wc*64 + nj*16 + lr;
                float v = acc[mi][nj][r] + bias[n];
                if (ACT == 1) v = gelu_f(v);
                if (FINAL) {
                    const size_t idx = (size_t)m * Nn + n;
                    v = fusedp[idx] + alpha * v + 0.5f * beta * (r1[idx] + r2[idx]);
                }
                if (OUT == 0) ((float*)Cv)[(size_t)m * Nn + n] = v;
                else          ((ushort*)Cv)[(size_t)m * Nn + n] = f2bf(v);
            }
        }
    }
}

// ---------------------------------------------------------------------------
// weight convert+transpose: Wt[n][k] = bf16(W[k][n]); 8 weights via blockIdx.z
// ---------------------------------------------------------------------------
__global__ __launch_bounds__(256) void cvtw_k(
    const float* __restrict__ w0, const float* __restrict__ w1,
    const float* __restrict__ w2, const float* __restrict__ w3,
    const float* __restrict__ w4, const float* __restrict__ w5,
    const float* __restrict__ w6, const float* __restrict__ w7,
    ushort* __restrict__ dst)
{
    __shared__ ushort T[64][72];
    const int id = blockIdx.z;
    int K, Nn, off;
    const float* src;
    switch (id) {
        case 0: src = w0; K = 512;  Nn = 1536; off = WOFF_SQ;    break;
        case 1: src = w1; K = 512;  Nn = 1536; off = WOFF_PQ;    break;
        case 2: src = w2; K = 512;  Nn = 512;  off = WOFF_SPROJ; break;
        case 3: src = w3; K = 512;  Nn = 512;  off = WOFF_PPROJ; break;
        case 4: src = w4; K = 512;  Nn = 1024; off = WOFF_VF1;   break;
        case 5: src = w5; K = 1024; Nn = 512;  off = WOFF_VF2;   break;
        case 6: src = w6; K = 512;  Nn = 1024; off = WOFF_FR1;   break;
        default: src = w7; K = 1024; Nn = 512; off = WOFF_FR2;   break;
    }
    const int n0 = blockIdx.x * 64, k0 = blockIdx.y * 64;
    if (n0 >= Nn || k0 >= K) return;
    const int t = threadIdx.x;
    const int q = t >> 6, e = t & 63;
    #pragma unroll 4
    for (int i = 0; i < 16; ++i) {
        const int kl = q * 16 + i;
        T[e][kl] = f2bf(src[(size_t)(k0 + kl) * Nn + n0 + e]);
    }
    __syncthreads();
    #pragma unroll 4
    for (int i = 0; i < 16; ++i) {
        const int nl = q * 16 + i;
        dst[(size_t)off + (size_t)(n0 + nl) * K + k0 + e] = T[nl][e];
    }
}

// ---------------------------------------------------------------------------
// elementwise f32 -> bf16 (optionally sum of two inputs); 8 elems/thread
// ---------------------------------------------------------------------------
template <bool ADD>
__global__ __launch_bounds__(256) void cvt_k(const float* __restrict__ a,
                                             const float* __restrict__ b,
                                             ushort* __restrict__ dst)
{
    const size_t i = ((size_t)blockIdx.x * 256 + threadIdx.x) * 8;
    float4 x0 = *reinterpret_cast<const float4*>(a + i);
    float4 x1 = *reinterpret_cast<const float4*>(a + i + 4);
    if (ADD) {
        const float4 y0 = *reinterpret_cast<const float4*>(b + i);
        const float4 y1 = *reinterpret_cast<const float4*>(b + i + 4);
        x0.x += y0.x; x0.y += y0.y; x0.z += y0.z; x0.w += y0.w;
        x1.x += y1.x; x1.y += y1.y; x1.z += y1.z; x1.w += y1.w;
    }
    FragU o;
    o.u[0] = pack2(x0.x, x0.y);
    o.u[1] = pack2(x0.z, x0.w);
    o.u[2] = pack2(x1.x, x1.y);
    o.u[3] = pack2(x1.z, x1.w);
    *reinterpret_cast<uint4*>(dst + i) = o.u4;
}

// ---------------------------------------------------------------------------
// In-place row LayerNorm over 1536, float4-vectorized
// ---------------------------------------------------------------------------
__global__ __launch_bounds__(256) void ln_k(float* __restrict__ x,
                                            const float* __restrict__ g,
                                            const float* __restrict__ b)
{
    __shared__ float red[4];
    float* xr = x + (size_t)blockIdx.x * D3_;
    float s = 0.f, ss = 0.f;
    for (int j = threadIdx.x * 4; j < D3_; j += 1024) {
        const float4 v = *reinterpret_cast<const float4*>(xr + j);
        s += v.x + v.y + v.z + v.w;
        ss += v.x*v.x + v.y*v.y + v.z*v.z + v.w*v.w;
    }
    s = blk_sum(s, red);
    ss = blk_sum(ss, red);
    const float mu = s * (1.0f / D3_);
    const float var = ss * (1.0f / D3_) - mu * mu;
    const float rs = rsqrtf(var + 1e-5f);
    for (int j = threadIdx.x * 4; j < D3_; j += 1024) {
        float4 v = *reinterpret_cast<const float4*>(xr + j);
        const float4 gv = *reinterpret_cast<const float4*>(g + j);
        const float4 bv = *reinterpret_cast<const float4*>(b + j);
        v.x = (v.x - mu) * rs * gv.x + bv.x;
        v.y = (v.y - mu) * rs * gv.y + bv.y;
        v.z = (v.z - mu) * rs * gv.z + bv.z;
        v.w = (v.w - mu) * rs * gv.w + bv.w;
        *reinterpret_cast<float4*>(xr + j) = v;
    }
}

// ---------------------------------------------------------------------------
// prep: l2norm K -> bf16 Kb[bh][n][64]; V -> bf16 transposed Vt[bh][d][1024]
// ---------------------------------------------------------------------------
__global__ __launch_bounds__(256) void prep_k(const float* __restrict__ qkv,
                                              ushort* __restrict__ Kb,
                                              ushort* __restrict__ Vt)
{
    __shared__ ushort Vs[64 * 72];
    const int nb = blockIdx.x & 15;
    const int h  = (blockIdx.x >> 4) & 7;
    const int b  = blockIdx.x >> 7;
    const int bh = b * 8 + h;
    const int n0 = nb * 64;
    const int w = threadIdx.x >> 6;
    const int l = threadIdx.x & 63;

    #pragma unroll 4
    for (int i = 0; i < 16; ++i) {
        const int row = w * 16 + i;
        const float* base = qkv + ((size_t)(b * N_) + n0 + row) * D3_ + h * HD_;
        const float kvl = base[D_ + l];
        const float vvl = base[2 * D_ + l];
        float ssq = kvl * kvl;
        #pragma unroll
        for (int off = 32; off; off >>= 1) ssq += __shfl_xor(ssq, off);
        const float sc = 1.0f / fmaxf(sqrtf(ssq), 1e-12f);
        Kb[((size_t)bh * N_ + n0 + row) * HD_ + l] = f2bf(kvl * sc);
        Vs[row * 72 + l] = f2bf(vvl);
    }
    __syncthreads();
    const int d = threadIdx.x >> 2, seg = threadIdx.x & 3;
    ushort tmp[16];
    #pragma unroll
    for (int i = 0; i < 16; ++i) tmp[i] = Vs[(seg * 16 + i) * 72 + d];
    ushort* dst = Vt + ((size_t)bh * HD_ + d) * N_ + n0 + seg * 16;
    *reinterpret_cast<uint4*>(dst)     = *reinterpret_cast<uint4*>(&tmp[0]);
    *reinterpret_cast<uint4*>(dst + 8) = *reinterpret_cast<uint4*>(&tmp[8]);
}

// ---------------------------------------------------------------------------
// Flash-style cosine attention, bf16 MFMA, swapped QK^T; OUTPUT NOW bf16.
// ---------------------------------------------------------------------------
__global__ __launch_bounds__(256) void fattn_k(const float* __restrict__ qkv,
                                               const ushort* __restrict__ Kb,
                                               const ushort* __restrict__ Vt,
                                               const float* __restrict__ temp,
                                               ushort* __restrict__ out)
{
    __shared__ ushort Ks[64 * 72];
    __shared__ ushort Vs[64 * 72];
    const int tid = threadIdx.x;
    const int nb = blockIdx.x & 15;
    const int h  = (blockIdx.x >> 4) & 7;
    const int b  = blockIdx.x >> 7;
    const int bh = b * 8 + h;
    const int n0 = nb * 64;
    const int w  = tid >> 6;
    const int l  = tid & 63;
    const int lr = l & 15;
    const int g  = l >> 4;
    const float t = temp[h];
    const float mabs = fabsf(t);

    const float* qrow = qkv + ((size_t)(b * N_) + n0 + w * 16 + lr) * D3_ + h * HD_;
    float qv[16];
    {
        const float4 q0 = *reinterpret_cast<const float4*>(qrow + 8 * g);
        const float4 q1 = *reinterpret_cast<const float4*>(qrow + 8 * g + 4);
        const float4 q2 = *reinterpret_cast<const float4*>(qrow + 32 + 8 * g);
        const float4 q3 = *reinterpret_cast<const float4*>(qrow + 32 + 8 * g + 4);
        qv[0]=q0.x; qv[1]=q0.y; qv[2]=q0.z; qv[3]=q0.w;
        qv[4]=q1.x; qv[5]=q1.y; qv[6]=q1.z; qv[7]=q1.w;
        qv[8]=q2.x; qv[9]=q2.y; qv[10]=q2.z; qv[11]=q2.w;
        qv[12]=q3.x; qv[13]=q3.y; qv[14]=q3.z; qv[15]=q3.w;
    }
    float ssq = 0.f;
    #pragma unroll
    for (int e = 0; e < 16; ++e) ssq += qv[e] * qv[e];
    ssq += __shfl_xor(ssq, 16);
    ssq += __shfl_xor(ssq, 32);
    const float qscale = t / fmaxf(sqrtf(ssq), 1e-12f);
    FragU qf0, qf1;
    #pragma unroll
    for (int e = 0; e < 8; ++e) {
        qf0.s[e] = f2bf(qv[e] * qscale);
        qf1.s[e] = f2bf(qv[8 + e] * qscale);
    }

    f32x4 O0 = {0.f,0.f,0.f,0.f}, O1 = {0.f,0.f,0.f,0.f};
    f32x4 O2 = {0.f,0.f,0.f,0.f}, O3 = {0.f,0.f,0.f,0.f};
    float lsum = 0.f;

    const ushort* kbase = Kb + (size_t)bh * N_ * HD_;
    const ushort* vbase = Vt + (size_t)bh * HD_ * N_;

    for (int kt = 0; kt < 16; ++kt) {
        __syncthreads();
        {
            const ushort* ksrc = kbase + (size_t)(kt * 64) * HD_;
            const ushort* vsrc = vbase + kt * 64;
            #pragma unroll
            for (int i = 0; i < 2; ++i) {
                const int c = tid + i * 256;
                const int row = c >> 3, c8 = (c & 7) * 8;
                *reinterpret_cast<uint4*>(&Ks[row * 72 + c8]) =
                    *reinterpret_cast<const uint4*>(ksrc + row * HD_ + c8);
            }
            #pragma unroll
            for (int i = 0; i < 2; ++i) {
                const int c = tid + i * 256;
                const int d = c >> 3, c8 = (c & 7) * 8;
                *reinterpret_cast<uint4*>(&Vs[d * 72 + c8]) =
                    *reinterpret_cast<const uint4*>(vsrc + (size_t)d * N_ + c8);
            }
        }
        __syncthreads();

        float p[4][4];
        #pragma unroll
        for (int j = 0; j < 4; ++j) {
            f32x4 s = {0.f,0.f,0.f,0.f};
            FragU ka, kc;
            ka.u4 = *reinterpret_cast<const uint4*>(&Ks[(j * 16 + lr) * 72 + 8 * g]);
            kc.u4 = *reinterpret_cast<const uint4*>(&Ks[(j * 16 + lr) * 72 + 32 + 8 * g]);
            s = __builtin_amdgcn_mfma_f32_16x16x32_bf16(ka.v, qf0.v, s, 0, 0, 0);
            s = __builtin_amdgcn_mfma_f32_16x16x32_bf16(kc.v, qf1.v, s, 0, 0, 0);
            #pragma unroll
            for (int r = 0; r < 4; ++r) {
                const float pv = __expf(s[r] - mabs);
                p[j][r] = pv;
                lsum += pv;
            }
        }

        #pragma unroll
        for (int ks = 0; ks < 2; ++ks) {
            FragU pa;
            pa.u[0] = pack2(p[2 * ks][0],     p[2 * ks][1]);
            pa.u[1] = pack2(p[2 * ks][2],     p[2 * ks][3]);
            pa.u[2] = pack2(p[2 * ks + 1][0], p[2 * ks + 1][1]);
            pa.u[3] = pack2(p[2 * ks + 1][2], p[2 * ks + 1][3]);
            #pragma unroll
            for (int s4 = 0; s4 < 4; ++s4) {
                FragU vb;
                const int vi = (lr + 16 * s4) * 72 + ks * 32 + 4 * g;
                *reinterpret_cast<uint2*>(&vb.u[0]) =
                    *reinterpret_cast<const uint2*>(&Vs[vi]);
                *reinterpret_cast<uint2*>(&vb.u[2]) =
                    *reinterpret_cast<const uint2*>(&Vs[vi + 16]);
                f32x4& Oc = (s4 == 0) ? O0 : (s4 == 1) ? O1 : (s4 == 2) ? O2 : O3;
                Oc = __builtin_amdgcn_mfma_f32_16x16x32_bf16(pa.v, vb.v, Oc, 0, 0, 0);
            }
        }
    }

    lsum += __shfl_xor(lsum, 16);
    lsum += __shfl_xor(lsum, 32);
    const float inv = 1.0f / lsum;
    ushort* outp = out + ((size_t)(b * N_) + n0 + w * 16) * D_ + h * HD_;
    #pragma unroll
    for (int r = 0; r < 4; ++r) {
        const float invr = __shfl(inv, 4 * g + r);
        ushort* orow = outp + (size_t)(4 * g + r) * D_;
        orow[0 * 16 + lr] = f2bf(O0[r] * invr);
        orow[1 * 16 + lr] = f2bf(O1[r] * invr);
        orow[2 * 16 + lr] = f2bf(O2[r] * invr);
        orow[3 * 16 + lr] = f2bf(O3[r] * invr);
    }
}

// ---------------------------------------------------------------------------
// Partial column sums for gate means (unchanged)
// ---------------------------------------------------------------------------
__global__ __launch_bounds__(256) void means_k(const float* __restrict__ spec,
                                               const float* __restrict__ spat,
                                               float* __restrict__ Gp)
{
    const int b = blockIdx.x >> 3;
    const int ch = blockIdx.x & 7;
    const int n0 = ch * 128;
    for (int d = threadIdx.x; d < D_; d += 256) {
        float s1 = 0.f, s2 = 0.f;
        for (int n = 0; n < 128; ++n) {
            const size_t idx = ((size_t)(b * N_) + n0 + n) * D_ + d;
            s1 += spec[idx];
            s2 += spat[idx];
        }
        Gp[(size_t)blockIdx.x * 1024 + d] = s1;
        Gp[(size_t)blockIdx.x * 1024 + 512 + d] = s2;
    }
}

// ---------------------------------------------------------------------------
// Gate MLP (unchanged)
// ---------------------------------------------------------------------------
__global__ __launch_bounds__(256) void gate_k(
    const float* __restrict__ Gp, const float* __restrict__ w1,
    const float* __restrict__ b1, const float* __restrict__ lng,
    const float* __restrict__ lnb, const float* __restrict__ w2,
    const float* __restrict__ b2, float* __restrict__ gate)
{
    __shared__ float xs[1024];
    __shared__ float red[4];
    const int b = blockIdx.x, tid = threadIdx.x;
    for (int j = tid; j < 1024; j += 256) {
        float s = 0.f;
        for (int c = 0; c < 8; ++c) s += Gp[(size_t)(b * 8 + c) * 1024 + j];
        xs[j] = s * (1.0f / N_);
    }
    __syncthreads();
    float y[2];
    #pragma unroll
    for (int u = 0; u < 2; ++u) {
        const int jj = tid + u * 256;
        float acc = b1[jj];
        for (int k = 0; k < 1024; ++k) acc += xs[k] * w1[(size_t)k * 512 + jj];
        y[u] = acc;
    }
    const float s = blk_sum(y[0] + y[1], red);
    const float ss = blk_sum(y[0] * y[0] + y[1] * y[1], red);
    const float mu = s * (1.0f / 512.0f);
    const float var = ss * (1.0f / 512.0f) - mu * mu;
    const float rs = rsqrtf(var + 1e-5f);
    float p0 = 0.f, p1 = 0.f, p2 = 0.f;
    #pragma unroll
    for (int u = 0; u < 2; ++u) {
        const int jj = tid + u * 256;
        const float z = gelu_f((y[u] - mu) * rs * lng[jj] + lnb[jj]);
        p0 += z * w2[jj * 3 + 0];
        p1 += z * w2[jj * 3 + 1];
        p2 += z * w2[jj * 3 + 2];
    }
    p0 = blk_sum(p0, red);
    p1 = blk_sum(p1, red);
    p2 = blk_sum(p2, red);
    if (tid == 0) {
        p0 += b2[0]; p1 += b2[1]; p2 += b2[2];
        const float m = fmaxf(p0, fmaxf(p1, p2));
        const float e0 = expf(p0 - m), e1 = expf(p1 - m), e2 = expf(p2 - m);
        const float inv = 1.0f / (e0 + e1 + e2);
        gate[b * 3 + 0] = e0 * inv;
        gate[b * 3 + 1] = e1 * inv;
        gate[b * 3 + 2] = e2 * inv;
    }
}

// ---------------------------------------------------------------------------
// fused = g0*spec + g1*spat + g2*vol; writes f32 AND bf16 copies
// ---------------------------------------------------------------------------
__global__ __launch_bounds__(256) void fuse_k(
    const float* __restrict__ spec, const float* __restrict__ spat,
    const float* __restrict__ vol, const float* __restrict__ gate,
    float* __restrict__ fusedF, ushort* __restrict__ fb)
{
    const size_t i4 = ((size_t)blockIdx.x * 256 + threadIdx.x) * 4;
    const int b = (int)(i4 >> 19);
    const float g0 = gate[b * 3 + 0], g1 = gate[b * 3 + 1], g2 = gate[b * 3 + 2];
    const float4 a = *reinterpret_cast<const float4*>(spec + i4);
    const float4 c = *reinterpret_cast<const float4*>(spat + i4);
    const float4 v = *reinterpret_cast<const float4*>(vol + i4);
    float4 o;
    o.x = g0 * a.x + g1 * c.x + g2 * v.x;
    o.y = g0 * a.y + g1 * c.y + g2 * v.y;
    o.z = g0 * a.z + g1 * c.z + g2 * v.z;
    o.w = g0 * a.w + g1 * c.w + g2 * v.w;
    *reinterpret_cast<float4*>(fusedF + i4) = o;
    union { ushort s[4]; uint2 u; } ob;
    ob.s[0] = f2bf(o.x); ob.s[1] = f2bf(o.y);
    ob.s[2] = f2bf(o.z); ob.s[3] = f2bf(o.w);
    *reinterpret_cast<uint2*>(fb + i4) = ob.u;
}

// ---------------------------------------------------------------------------
extern "C" void kernel_launch(void* const* d_in, const int* in_sizes, int n_in,
                              void* d_out, int out_size, void* d_ws, size_t ws_size,
                              hipStream_t stream)
{
    const float* hsi    = (const float*)d_in[0];
    const float* lidar  = (const float*)d_in[1];
    const float* temp   = (const float*)d_in[2];
    const float* sq_w   = (const float*)d_in[3];
    const float* sq_b   = (const float*)d_in[4];
    const float* sq_lng = (const float*)d_in[5];
    const float* sq_lnb = (const float*)d_in[6];
    const float* sproj_w = (const float*)d_in[7];
    const float* sproj_b = (const float*)d_in[8];
    const float* pq_w   = (const float*)d_in[9];
    const float* pq_b   = (const float*)d_in[10];
    const float* pq_lng = (const float*)d_in[11];
    const float* pq_lnb = (const float*)d_in[12];
    const float* pproj_w = (const float*)d_in[13];
    const float* pproj_b = (const float*)d_in[14];
    const float* vf_w1  = (const float*)d_in[15];
    const float* vf_b1  = (const float*)d_in[16];
    const float* vf_w2  = (const float*)d_in[17];
    const float* vf_b2  = (const float*)d_in[18];
    const float* ag_w1  = (const float*)d_in[19];
    const float* ag_b1  = (const float*)d_in[20];
    const float* ag_lng = (const float*)d_in[21];
    const float* ag_lnb = (const float*)d_in[22];
    const float* ag_w2  = (const float*)d_in[23];
    const float* ag_b2  = (const float*)d_in[24];
    const float* fr_w1  = (const float*)d_in[25];
    const float* fr_b1  = (const float*)d_in[26];
    const float* fr_w2  = (const float*)d_in[27];
    const float* fr_b2  = (const float*)d_in[28];
    const float* alpha  = (const float*)d_in[29];
    const float* beta   = (const float*)d_in[30];
    float* out = (float*)d_out;

    // ---- workspace layout (112 MB total) ----
    float* wsA    = (float*)d_ws;            // [8192][1536] qkv f32 (12.58M f)
    float* vol    = wsA;                     //   after attn: [8192][512] volumetric
    float* fusedF = wsA + 4194304;           //   [8192][512] fused f32
    float* Gp     = wsA + 8388608;           //   [64][1024] gate partials
    float* gate   = Gp + 65536;              //   [8][3]
    float* wsC    = wsA + 12582912;          // [8192][512] out_spectral f32
    float* wsD    = wsC + 4194304;           // [8192][512] out_spatial f32
    ushort* KVH   = (ushort*)(wsD + 4194304);// 8.39M ush: Kb+Vt, later Hb
    ushort* Kb    = KVH;                     // [64][1024][64]
    ushort* Vt    = KVH + 4194304;           // [64][64][1024]
    ushort* Hb    = KVH;                     // [8192][1024] bf16 MLP hidden
    ushort* Bb1   = KVH + 8388608;           // [8192][512] bf16 activation buf
    ushort* Wb    = Bb1 + 4194304;           // 4.19M ush bf16 weights (transposed)

    const dim3 blk(256);
    const dim3 g_qkv(12, 64);     // N=1536, M=8192
    const dim3 g_d(4, 64);        // N=512
    const dim3 g_2d(8, 64);       // N=1024
    const int g_attn = B_ * H_ * (N_ / 64);   // 1024

    // ---- weight + input conversion
    cvtw_k<<<dim3(24, 16, 8), blk, 0, stream>>>(sq_w, pq_w, sproj_w, pproj_w,
                                                vf_w1, vf_w2, fr_w1, fr_w2, Wb);
    cvt_k<false><<<2048, blk, 0, stream>>>(hsi, nullptr, Bb1);

    // ---- spectral branch
    bgemm_k<0,0,false><<<g_qkv, blk, 0, stream>>>(Bb1, Wb + WOFF_SQ, sq_b, wsA,
        M_, D3_, D_, nullptr, nullptr, nullptr, nullptr, nullptr);
    ln_k<<<M_, blk, 0, stream>>>(wsA, sq_lng, sq_lnb);
    prep_k<<<g_attn, blk, 0, stream>>>(wsA, Kb, Vt);
    fattn_k<<<g_attn, blk, 0, stream>>>(wsA, Kb, Vt, temp, Bb1);
    bgemm_k<0,0,false><<<g_d, blk, 0, stream>>>(Bb1, Wb + WOFF_SPROJ, sproj_b, wsC,
        M_, D_, D_, nullptr, nullptr, nullptr, nullptr, nullptr);

    // ---- spatial branch
    cvt_k<false><<<2048, blk, 0, stream>>>(lidar, nullptr, Bb1);
    bgemm_k<0,0,false><<<g_qkv, blk, 0, stream>>>(Bb1, Wb + WOFF_PQ, pq_b, wsA,
        M_, D3_, D_, nullptr, nullptr, nullptr, nullptr, nullptr);
    ln_k<<<M_, blk, 0, stream>>>(wsA, pq_lng, pq_lnb);
    prep_k<<<g_attn, blk, 0, stream>>>(wsA, Kb, Vt);
    fattn_k<<<g_attn, blk, 0, stream>>>(wsA, Kb, Vt, temp, Bb1);
    bgemm_k<0,0,false><<<g_d, blk, 0, stream>>>(Bb1, Wb + WOFF_PPROJ, pproj_b, wsD,
        M_, D_, D_, nullptr, nullptr, nullptr, nullptr, nullptr);

    // ---- volumetric MLP: Sb = bf16(spec+spat); Hb = gelu(Sb@vf_w1+b1); vol = Hb@vf_w2+b2
    cvt_k<true><<<2048, blk, 0, stream>>>(wsC, wsD, Bb1);
    bgemm_k<1,1,false><<<g_2d, blk, 0, stream>>>(Bb1, Wb + WOFF_VF1, vf_b1, Hb,
        M_, 1024, D_, nullptr, nullptr, nullptr, nullptr, nullptr);
    bgemm_k<0,0,false><<<g_d, blk, 0, stream>>>(Hb, Wb + WOFF_VF2, vf_b2, vol,
        M_, D_, 1024, nullptr, nullptr, nullptr, nullptr, nullptr);

    // ---- adaptive gate
    means_k<<<B_ * 8, blk, 0, stream>>>(wsC, wsD, Gp);
    gate_k<<<B_, blk, 0, stream>>>(Gp, ag_w1, ag_b1, ag_lng, ag_lnb, ag_w2, ag_b2, gate);
    fuse_k<<<4096, blk, 0, stream>>>(wsC, wsD, vol, gate, fusedF, Bb1);

    // ---- fused recal MLP + final combine
    bgemm_k<1,1,false><<<g_2d, blk, 0, stream>>>(Bb1, Wb + WOFF_FR1, fr_b1, Hb,
        M_, 1024, D_, nullptr, nullptr, nullptr, nullptr, nullptr);
    bgemm_k<0,0,true><<<g_d, blk, 0, stream>>>(Hb, Wb + WOFF_FR2, fr_b2, out,
        M_, D_, 1024, fusedF, hsi, lidar, alpha, beta);
}

// Round 4
// 441.777 us; speedup vs baseline: 13.1148x; 1.1033x over previous
//
#include <hip/hip_runtime.h>
#include <hip/hip_bf16.h>
#include <math.h>

#define B_   8
#define N_   1024
#define D_   512
#define H_   8
#define HD_  64
#define D3_  1536
#define M_   (B_ * N_)   // 8192 tokens

// bf16 weight-pool offsets (elements)
#define WOFF_SQ    0
#define WOFF_PQ    786432
#define WOFF_SPROJ 1572864
#define WOFF_PPROJ 1835008
#define WOFF_VF1   2097152
#define WOFF_VF2   2621440
#define WOFF_FR1   3145728
#define WOFF_FR2   3670016

typedef float f32x4 __attribute__((ext_vector_type(4)));
typedef __bf16 bf16x8 __attribute__((ext_vector_type(8)));

union FragU {
    uint4 u4;
    unsigned int u[4];
    ushort s[8];
    bf16x8 v;
};

static __device__ __forceinline__ ushort f2bf(float x) {
    union { __bf16 h; ushort u; } c;
    c.h = (__bf16)x;
    return c.u;
}

static __device__ __forceinline__ unsigned int pack2(float a, float b) {
    return (unsigned int)f2bf(a) | ((unsigned int)f2bf(b) << 16);
}

static __device__ __forceinline__ float gelu_f(float x) {
    return 0.5f * x * (1.0f + erff(x * 0.7071067811865475f));
}

// async global->LDS, 16B per lane; lds base must be wave-uniform
static __device__ __forceinline__ void gload16(const ushort* g, ushort* lds) {
    __builtin_amdgcn_global_load_lds(
        (const __attribute__((address_space(1))) void*)g,
        (__attribute__((address_space(3))) void*)lds, 16, 0, 0);
}

// block-wide sum, blockDim.x == 256 (4 waves)
static __device__ __forceinline__ float blk_sum(float v, float* red) {
    #pragma unroll
    for (int off = 32; off; off >>= 1) v += __shfl_xor(v, off);
    const int w = threadIdx.x >> 6;
    __syncthreads();
    if ((threadIdx.x & 63) == 0) red[w] = v;
    __syncthreads();
    return red[0] + red[1] + red[2] + red[3];
}

// ---------------------------------------------------------------------------
// bf16 MFMA GEMM: C[M,N] = epi(A[M,K] @ W[K,N] + bias),  W given as Wt[N][K].
// 128x128 tile, BK=32, 256 thr (4 waves, 2x2), 4x4 16x16 frags per wave.
// ---------------------------------------------------------------------------
template <int ACT, int OUT, bool FINAL>
__global__ __launch_bounds__(256) void bgemm_k(
    const ushort* __restrict__ A, const ushort* __restrict__ Wt,
    const float* __restrict__ bias, void* __restrict__ Cv,
    int M, int Nn, int K,
    const float* __restrict__ fusedp, const float* __restrict__ r1,
    const float* __restrict__ r2, const float* __restrict__ alphap,
    const float* __restrict__ betap)
{
    __shared__ ushort Asm[2][4096];
    __shared__ ushort Bsm[2][4096];
    const int tid = threadIdx.x;
    const int w = tid >> 6, l = tid & 63;
    const int m0 = blockIdx.y * 128, n0 = blockIdx.x * 128;
    const int wr = w >> 1, wc = w & 1;
    const int lr = l & 15, g = l >> 4;

    const int srow = (l & 15);
    const int skof = 8 * (l >> 4);

    f32x4 acc[4][4] = {};
    const int nt = K >> 5;

    const int c0 = 2 * w, c1 = 2 * w + 1;
    const int ar0 = (c0 >> 2) * 64 + (c0 & 3) * 16 + srow;
    const int ar1 = (c1 >> 2) * 64 + (c1 & 3) * 16 + srow;

    #define STAGE(buf, kt)                                                      \
        do {                                                                    \
            const int k0s = (kt) << 5;                                          \
            gload16(&A[(size_t)(m0 + ar0) * K + k0s + skof], &Asm[buf][c0*512]);\
            gload16(&A[(size_t)(m0 + ar1) * K + k0s + skof], &Asm[buf][c1*512]);\
            gload16(&Wt[(size_t)(n0 + ar0) * K + k0s + skof], &Bsm[buf][c0*512]);\
            gload16(&Wt[(size_t)(n0 + ar1) * K + k0s + skof], &Bsm[buf][c1*512]);\
        } while (0)

    STAGE(0, 0);
    __syncthreads();
    int cur = 0;
    for (int t = 0; t < nt; ++t) {
        if (t + 1 < nt) STAGE(cur ^ 1, t + 1);
        FragU af[4], bf4[4];
        #pragma unroll
        for (int mi = 0; mi < 4; ++mi)
            af[mi].u4 = *reinterpret_cast<const uint4*>(&Asm[cur][((wr*4 + mi)*64 + l)*8]);
        #pragma unroll
        for (int nj = 0; nj < 4; ++nj)
            bf4[nj].u4 = *reinterpret_cast<const uint4*>(&Bsm[cur][((wc*4 + nj)*64 + l)*8]);
        #pragma unroll
        for (int mi = 0; mi < 4; ++mi)
            #pragma unroll
            for (int nj = 0; nj < 4; ++nj)
                acc[mi][nj] = __builtin_amdgcn_mfma_f32_16x16x32_bf16(
                    af[mi].v, bf4[nj].v, acc[mi][nj], 0, 0, 0);
        __syncthreads();
        cur ^= 1;
    }
    #undef STAGE

    float alpha = 0.f, beta = 0.f;
    if (FINAL) { alpha = alphap[0]; beta = betap[0]; }
    #pragma unroll
    for (int mi = 0; mi < 4; ++mi) {
        #pragma unroll
        for (int r = 0; r < 4; ++r) {
            const int m = m0 + wr*64 + mi*16 + g*4 + r;
            #pragma unroll
            for (int nj = 0; nj < 4; ++nj) {
                const int n = n0 + wc*64 + nj*16 + lr;
                float v = acc[mi][nj][r] + bias[n];
                if (ACT == 1) v = gelu_f(v);
                if (FINAL) {
                    const size_t idx = (size_t)m * Nn + n;
                    v = fusedp[idx] + alpha * v + 0.5f * beta * (r1[idx] + r2[idx]);
                }
                if (OUT == 0) ((float*)Cv)[(size_t)m * Nn + n] = v;
                else          ((ushort*)Cv)[(size_t)m * Nn + n] = f2bf(v);
            }
        }
    }
}

// ---------------------------------------------------------------------------
// weight convert+transpose: Wt[n][k] = bf16(W[k][n]); 8 weights via blockIdx.z
// ---------------------------------------------------------------------------
__global__ __launch_bounds__(256) void cvtw_k(
    const float* __restrict__ w0, const float* __restrict__ w1,
    const float* __restrict__ w2, const float* __restrict__ w3,
    const float* __restrict__ w4, const float* __restrict__ w5,
    const float* __restrict__ w6, const float* __restrict__ w7,
    ushort* __restrict__ dst)
{
    __shared__ ushort T[64][72];
    const int id = blockIdx.z;
    int K, Nn, off;
    const float* src;
    switch (id) {
        case 0: src = w0; K = 512;  Nn = 1536; off = WOFF_SQ;    break;
        case 1: src = w1; K = 512;  Nn = 1536; off = WOFF_PQ;    break;
        case 2: src = w2; K = 512;  Nn = 512;  off = WOFF_SPROJ; break;
        case 3: src = w3; K = 512;  Nn = 512;  off = WOFF_PPROJ; break;
        case 4: src = w4; K = 512;  Nn = 1024; off = WOFF_VF1;   break;
        case 5: src = w5; K = 1024; Nn = 512;  off = WOFF_VF2;   break;
        case 6: src = w6; K = 512;  Nn = 1024; off = WOFF_FR1;   break;
        default: src = w7; K = 1024; Nn = 512; off = WOFF_FR2;   break;
    }
    const int n0 = blockIdx.x * 64, k0 = blockIdx.y * 64;
    if (n0 >= Nn || k0 >= K) return;
    const int t = threadIdx.x;
    const int q = t >> 6, e = t & 63;
    #pragma unroll 4
    for (int i = 0; i < 16; ++i) {
        const int kl = q * 16 + i;
        T[e][kl] = f2bf(src[(size_t)(k0 + kl) * Nn + n0 + e]);
    }
    __syncthreads();
    #pragma unroll 4
    for (int i = 0; i < 16; ++i) {
        const int nl = q * 16 + i;
        dst[(size_t)off + (size_t)(n0 + nl) * K + k0 + e] = T[nl][e];
    }
}

// ---------------------------------------------------------------------------
// elementwise f32 -> bf16 (optionally sum of two inputs); 8 elems/thread
// ---------------------------------------------------------------------------
template <bool ADD>
__global__ __launch_bounds__(256) void cvt_k(const float* __restrict__ a,
                                             const float* __restrict__ b,
                                             ushort* __restrict__ dst)
{
    const size_t i = ((size_t)blockIdx.x * 256 + threadIdx.x) * 8;
    float4 x0 = *reinterpret_cast<const float4*>(a + i);
    float4 x1 = *reinterpret_cast<const float4*>(a + i + 4);
    if (ADD) {
        const float4 y0 = *reinterpret_cast<const float4*>(b + i);
        const float4 y1 = *reinterpret_cast<const float4*>(b + i + 4);
        x0.x += y0.x; x0.y += y0.y; x0.z += y0.z; x0.w += y0.w;
        x1.x += y1.x; x1.y += y1.y; x1.z += y1.z; x1.w += y1.w;
    }
    FragU o;
    o.u[0] = pack2(x0.x, x0.y);
    o.u[1] = pack2(x0.z, x0.w);
    o.u[2] = pack2(x1.x, x1.y);
    o.u[3] = pack2(x1.z, x1.w);
    *reinterpret_cast<uint4*>(dst + i) = o.u4;
}

// ---------------------------------------------------------------------------
// In-place row LayerNorm over 1536, float4-vectorized
// ---------------------------------------------------------------------------
__global__ __launch_bounds__(256) void ln_k(float* __restrict__ x,
                                            const float* __restrict__ g,
                                            const float* __restrict__ b)
{
    __shared__ float red[4];
    float* xr = x + (size_t)blockIdx.x * D3_;
    float s = 0.f, ss = 0.f;
    for (int j = threadIdx.x * 4; j < D3_; j += 1024) {
        const float4 v = *reinterpret_cast<const float4*>(xr + j);
        s += v.x + v.y + v.z + v.w;
        ss += v.x*v.x + v.y*v.y + v.z*v.z + v.w*v.w;
    }
    s = blk_sum(s, red);
    ss = blk_sum(ss, red);
    const float mu = s * (1.0f / D3_);
    const float var = ss * (1.0f / D3_) - mu * mu;
    const float rs = rsqrtf(var + 1e-5f);
    for (int j = threadIdx.x * 4; j < D3_; j += 1024) {
        float4 v = *reinterpret_cast<const float4*>(xr + j);
        const float4 gv = *reinterpret_cast<const float4*>(g + j);
        const float4 bv = *reinterpret_cast<const float4*>(b + j);
        v.x = (v.x - mu) * rs * gv.x + bv.x;
        v.y = (v.y - mu) * rs * gv.y + bv.y;
        v.z = (v.z - mu) * rs * gv.z + bv.z;
        v.w = (v.w - mu) * rs * gv.w + bv.w;
        *reinterpret_cast<float4*>(xr + j) = v;
    }
}

// ---------------------------------------------------------------------------
// prep: l2norm K -> bf16 Kb[bh][n][64]; V -> bf16 transposed Vt[bh][d][1024]
// ---------------------------------------------------------------------------
__global__ __launch_bounds__(256) void prep_k(const float* __restrict__ qkv,
                                              ushort* __restrict__ Kb,
                                              ushort* __restrict__ Vt)
{
    __shared__ ushort Vs[64 * 72];
    const int nb = blockIdx.x & 15;
    const int h  = (blockIdx.x >> 4) & 7;
    const int b  = blockIdx.x >> 7;
    const int bh = b * 8 + h;
    const int n0 = nb * 64;
    const int w = threadIdx.x >> 6;
    const int l = threadIdx.x & 63;

    #pragma unroll 4
    for (int i = 0; i < 16; ++i) {
        const int row = w * 16 + i;
        const float* base = qkv + ((size_t)(b * N_) + n0 + row) * D3_ + h * HD_;
        const float kvl = base[D_ + l];
        const float vvl = base[2 * D_ + l];
        float ssq = kvl * kvl;
        #pragma unroll
        for (int off = 32; off; off >>= 1) ssq += __shfl_xor(ssq, off);
        const float sc = 1.0f / fmaxf(sqrtf(ssq), 1e-12f);
        Kb[((size_t)bh * N_ + n0 + row) * HD_ + l] = f2bf(kvl * sc);
        Vs[row * 72 + l] = f2bf(vvl);
    }
    __syncthreads();
    const int d = threadIdx.x >> 2, seg = threadIdx.x & 3;
    ushort tmp[16];
    #pragma unroll
    for (int i = 0; i < 16; ++i) tmp[i] = Vs[(seg * 16 + i) * 72 + d];
    ushort* dst = Vt + ((size_t)bh * HD_ + d) * N_ + n0 + seg * 16;
    *reinterpret_cast<uint4*>(dst)     = *reinterpret_cast<uint4*>(&tmp[0]);
    *reinterpret_cast<uint4*>(dst + 8) = *reinterpret_cast<uint4*>(&tmp[8]);
}

// ---------------------------------------------------------------------------
// Flash-style cosine attention, bf16 MFMA, swapped QK^T; output bf16.
// ---------------------------------------------------------------------------
__global__ __launch_bounds__(256) void fattn_k(const float* __restrict__ qkv,
                                               const ushort* __restrict__ Kb,
                                               const ushort* __restrict__ Vt,
                                               const float* __restrict__ temp,
                                               ushort* __restrict__ out)
{
    __shared__ ushort Ks[64 * 72];
    __shared__ ushort Vs[64 * 72];
    const int tid = threadIdx.x;
    const int nb = blockIdx.x & 15;
    const int h  = (blockIdx.x >> 4) & 7;
    const int b  = blockIdx.x >> 7;
    const int bh = b * 8 + h;
    const int n0 = nb * 64;
    const int w  = tid >> 6;
    const int l  = tid & 63;
    const int lr = l & 15;
    const int g  = l >> 4;
    const float t = temp[h];
    const float mabs = fabsf(t);

    const float* qrow = qkv + ((size_t)(b * N_) + n0 + w * 16 + lr) * D3_ + h * HD_;
    float qv[16];
    {
        const float4 q0 = *reinterpret_cast<const float4*>(qrow + 8 * g);
        const float4 q1 = *reinterpret_cast<const float4*>(qrow + 8 * g + 4);
        const float4 q2 = *reinterpret_cast<const float4*>(qrow + 32 + 8 * g);
        const float4 q3 = *reinterpret_cast<const float4*>(qrow + 32 + 8 * g + 4);
        qv[0]=q0.x; qv[1]=q0.y; qv[2]=q0.z; qv[3]=q0.w;
        qv[4]=q1.x; qv[5]=q1.y; qv[6]=q1.z; qv[7]=q1.w;
        qv[8]=q2.x; qv[9]=q2.y; qv[10]=q2.z; qv[11]=q2.w;
        qv[12]=q3.x; qv[13]=q3.y; qv[14]=q3.z; qv[15]=q3.w;
    }
    float ssq = 0.f;
    #pragma unroll
    for (int e = 0; e < 16; ++e) ssq += qv[e] * qv[e];
    ssq += __shfl_xor(ssq, 16);
    ssq += __shfl_xor(ssq, 32);
    const float qscale = t / fmaxf(sqrtf(ssq), 1e-12f);
    FragU qf0, qf1;
    #pragma unroll
    for (int e = 0; e < 8; ++e) {
        qf0.s[e] = f2bf(qv[e] * qscale);
        qf1.s[e] = f2bf(qv[8 + e] * qscale);
    }

    f32x4 O0 = {0.f,0.f,0.f,0.f}, O1 = {0.f,0.f,0.f,0.f};
    f32x4 O2 = {0.f,0.f,0.f,0.f}, O3 = {0.f,0.f,0.f,0.f};
    float lsum = 0.f;

    const ushort* kbase = Kb + (size_t)bh * N_ * HD_;
    const ushort* vbase = Vt + (size_t)bh * HD_ * N_;

    for (int kt = 0; kt < 16; ++kt) {
        __syncthreads();
        {
            const ushort* ksrc = kbase + (size_t)(kt * 64) * HD_;
            const ushort* vsrc = vbase + kt * 64;
            #pragma unroll
            for (int i = 0; i < 2; ++i) {
                const int c = tid + i * 256;
                const int row = c >> 3, c8 = (c & 7) * 8;
                *reinterpret_cast<uint4*>(&Ks[row * 72 + c8]) =
                    *reinterpret_cast<const uint4*>(ksrc + row * HD_ + c8);
            }
            #pragma unroll
            for (int i = 0; i < 2; ++i) {
                const int c = tid + i * 256;
                const int d = c >> 3, c8 = (c & 7) * 8;
                *reinterpret_cast<uint4*>(&Vs[d * 72 + c8]) =
                    *reinterpret_cast<const uint4*>(vsrc + (size_t)d * N_ + c8);
            }
        }
        __syncthreads();

        float p[4][4];
        #pragma unroll
        for (int j = 0; j < 4; ++j) {
            f32x4 s = {0.f,0.f,0.f,0.f};
            FragU ka, kc;
            ka.u4 = *reinterpret_cast<const uint4*>(&Ks[(j * 16 + lr) * 72 + 8 * g]);
            kc.u4 = *reinterpret_cast<const uint4*>(&Ks[(j * 16 + lr) * 72 + 32 + 8 * g]);
            s = __builtin_amdgcn_mfma_f32_16x16x32_bf16(ka.v, qf0.v, s, 0, 0, 0);
            s = __builtin_amdgcn_mfma_f32_16x16x32_bf16(kc.v, qf1.v, s, 0, 0, 0);
            #pragma unroll
            for (int r = 0; r < 4; ++r) {
                const float pv = __expf(s[r] - mabs);
                p[j][r] = pv;
                lsum += pv;
            }
        }

        #pragma unroll
        for (int ks = 0; ks < 2; ++ks) {
            FragU pa;
            pa.u[0] = pack2(p[2 * ks][0],     p[2 * ks][1]);
            pa.u[1] = pack2(p[2 * ks][2],     p[2 * ks][3]);
            pa.u[2] = pack2(p[2 * ks + 1][0], p[2 * ks + 1][1]);
            pa.u[3] = pack2(p[2 * ks + 1][2], p[2 * ks + 1][3]);
            #pragma unroll
            for (int s4 = 0; s4 < 4; ++s4) {
                FragU vb;
                const int vi = (lr + 16 * s4) * 72 + ks * 32 + 4 * g;
                *reinterpret_cast<uint2*>(&vb.u[0]) =
                    *reinterpret_cast<const uint2*>(&Vs[vi]);
                *reinterpret_cast<uint2*>(&vb.u[2]) =
                    *reinterpret_cast<const uint2*>(&Vs[vi + 16]);
                f32x4& Oc = (s4 == 0) ? O0 : (s4 == 1) ? O1 : (s4 == 2) ? O2 : O3;
                Oc = __builtin_amdgcn_mfma_f32_16x16x32_bf16(pa.v, vb.v, Oc, 0, 0, 0);
            }
        }
    }

    lsum += __shfl_xor(lsum, 16);
    lsum += __shfl_xor(lsum, 32);
    const float inv = 1.0f / lsum;
    ushort* outp = out + ((size_t)(b * N_) + n0 + w * 16) * D_ + h * HD_;
    #pragma unroll
    for (int r = 0; r < 4; ++r) {
        const float invr = __shfl(inv, 4 * g + r);
        ushort* orow = outp + (size_t)(4 * g + r) * D_;
        orow[0 * 16 + lr] = f2bf(O0[r] * invr);
        orow[1 * 16 + lr] = f2bf(O1[r] * invr);
        orow[2 * 16 + lr] = f2bf(O2[r] * invr);
        orow[3 * 16 + lr] = f2bf(O3[r] * invr);
    }
}

// ---------------------------------------------------------------------------
// Partial column sums for gate means: 32-row chunks, grid = B*32 = 256 blocks
// Gp[(b*32+c)*1024 + {d | 512+d}]
// ---------------------------------------------------------------------------
__global__ __launch_bounds__(256) void means_k(const float* __restrict__ spec,
                                               const float* __restrict__ spat,
                                               float* __restrict__ Gp)
{
    const int b = blockIdx.x >> 5;
    const int ch = blockIdx.x & 31;
    const int n0 = ch * 32;
    for (int d = threadIdx.x; d < D_; d += 256) {
        float s1 = 0.f, s2 = 0.f;
        #pragma unroll 4
        for (int n = 0; n < 32; ++n) {
            const size_t idx = ((size_t)(b * N_) + n0 + n) * D_ + d;
            s1 += spec[idx];
            s2 += spat[idx];
        }
        Gp[(size_t)blockIdx.x * 1024 + d] = s1;
        Gp[(size_t)blockIdx.x * 1024 + 512 + d] = s2;
    }
}

// ---------------------------------------------------------------------------
// gate GEMV: y[b][512] = mean-vec(xs) @ ag_w1 + b1.
// grid = (8 jchunks, 8 b), 256 thr: jj = jc*64+(t&63), 4 k-segments of 256.
// ---------------------------------------------------------------------------
__global__ __launch_bounds__(256) void gate1_k(const float* __restrict__ Gp,
                                               const float* __restrict__ w1,
                                               const float* __restrict__ b1,
                                               float* __restrict__ y)
{
    __shared__ float xs[1024];
    __shared__ float red[4][64];
    const int jc = blockIdx.x, b = blockIdx.y, tid = threadIdx.x;
    for (int k = tid; k < 1024; k += 256) {
        float s = 0.f;
        #pragma unroll 8
        for (int c = 0; c < 32; ++c) s += Gp[(size_t)(b * 32 + c) * 1024 + k];
        xs[k] = s * (1.0f / N_);
    }
    __syncthreads();
    const int jl = tid & 63;
    const int jj = jc * 64 + jl;
    const int seg = tid >> 6;
    float acc = 0.f;
    const float* wp = w1 + (size_t)(seg * 256) * 512 + jj;
    const float* xp = xs + seg * 256;
    #pragma unroll 8
    for (int k = 0; k < 256; ++k) acc += xp[k] * wp[(size_t)k * 512];
    red[seg][jl] = acc;
    __syncthreads();
    if (tid < 64)
        y[b * 512 + jc * 64 + tid] =
            red[0][tid] + red[1][tid] + red[2][tid] + red[3][tid] + b1[jc * 64 + tid];
}

// ---------------------------------------------------------------------------
// gate tail: LN(512) -> GELU -> @ag_w2[512,3]+b2 -> softmax. grid = 8 blocks.
// ---------------------------------------------------------------------------
__global__ __launch_bounds__(256) void gate2_k(const float* __restrict__ y,
                                               const float* __restrict__ lng,
                                               const float* __restrict__ lnb,
                                               const float* __restrict__ w2,
                                               const float* __restrict__ b2,
                                               float* __restrict__ gate)
{
    __shared__ float red[4];
    const int b = blockIdx.x, tid = threadIdx.x;
    const float v0 = y[b * 512 + tid];
    const float v1 = y[b * 512 + 256 + tid];
    const float s = blk_sum(v0 + v1, red);
    const float ss = blk_sum(v0 * v0 + v1 * v1, red);
    const float mu = s * (1.0f / 512.0f);
    const float var = ss * (1.0f / 512.0f) - mu * mu;
    const float rs = rsqrtf(var + 1e-5f);
    const float z0 = gelu_f((v0 - mu) * rs * lng[tid] + lnb[tid]);
    const float z1 = gelu_f((v1 - mu) * rs * lng[tid + 256] + lnb[tid + 256]);
    float p0 = z0 * w2[tid * 3 + 0] + z1 * w2[(tid + 256) * 3 + 0];
    float p1 = z0 * w2[tid * 3 + 1] + z1 * w2[(tid + 256) * 3 + 1];
    float p2 = z0 * w2[tid * 3 + 2] + z1 * w2[(tid + 256) * 3 + 2];
    p0 = blk_sum(p0, red);
    p1 = blk_sum(p1, red);
    p2 = blk_sum(p2, red);
    if (tid == 0) {
        p0 += b2[0]; p1 += b2[1]; p2 += b2[2];
        const float m = fmaxf(p0, fmaxf(p1, p2));
        const float e0 = expf(p0 - m), e1 = expf(p1 - m), e2 = expf(p2 - m);
        const float inv = 1.0f / (e0 + e1 + e2);
        gate[b * 3 + 0] = e0 * inv;
        gate[b * 3 + 1] = e1 * inv;
        gate[b * 3 + 2] = e2 * inv;
    }
}

// ---------------------------------------------------------------------------
// fused = g0*spec + g1*spat + g2*vol; writes f32 AND bf16 copies
// ---------------------------------------------------------------------------
__global__ __launch_bounds__(256) void fuse_k(
    const float* __restrict__ spec, const float* __restrict__ spat,
    const float* __restrict__ vol, const float* __restrict__ gate,
    float* __restrict__ fusedF, ushort* __restrict__ fb)
{
    const size_t i4 = ((size_t)blockIdx.x * 256 + threadIdx.x) * 4;
    const int b = (int)(i4 >> 19);
    const float g0 = gate[b * 3 + 0], g1 = gate[b * 3 + 1], g2 = gate[b * 3 + 2];
    const float4 a = *reinterpret_cast<const float4*>(spec + i4);
    const float4 c = *reinterpret_cast<const float4*>(spat + i4);
    const float4 v = *reinterpret_cast<const float4*>(vol + i4);
    float4 o;
    o.x = g0 * a.x + g1 * c.x + g2 * v.x;
    o.y = g0 * a.y + g1 * c.y + g2 * v.y;
    o.z = g0 * a.z + g1 * c.z + g2 * v.z;
    o.w = g0 * a.w + g1 * c.w + g2 * v.w;
    *reinterpret_cast<float4*>(fusedF + i4) = o;
    union { ushort s[4]; uint2 u; } ob;
    ob.s[0] = f2bf(o.x); ob.s[1] = f2bf(o.y);
    ob.s[2] = f2bf(o.z); ob.s[3] = f2bf(o.w);
    *reinterpret_cast<uint2*>(fb + i4) = ob.u;
}

// ---------------------------------------------------------------------------
extern "C" void kernel_launch(void* const* d_in, const int* in_sizes, int n_in,
                              void* d_out, int out_size, void* d_ws, size_t ws_size,
                              hipStream_t stream)
{
    const float* hsi    = (const float*)d_in[0];
    const float* lidar  = (const float*)d_in[1];
    const float* temp   = (const float*)d_in[2];
    const float* sq_w   = (const float*)d_in[3];
    const float* sq_b   = (const float*)d_in[4];
    const float* sq_lng = (const float*)d_in[5];
    const float* sq_lnb = (const float*)d_in[6];
    const float* sproj_w = (const float*)d_in[7];
    const float* sproj_b = (const float*)d_in[8];
    const float* pq_w   = (const float*)d_in[9];
    const float* pq_b   = (const float*)d_in[10];
    const float* pq_lng = (const float*)d_in[11];
    const float* pq_lnb = (const float*)d_in[12];
    const float* pproj_w = (const float*)d_in[13];
    const float* pproj_b = (const float*)d_in[14];
    const float* vf_w1  = (const float*)d_in[15];
    const float* vf_b1  = (const float*)d_in[16];
    const float* vf_w2  = (const float*)d_in[17];
    const float* vf_b2  = (const float*)d_in[18];
    const float* ag_w1  = (const float*)d_in[19];
    const float* ag_b1  = (const float*)d_in[20];
    const float* ag_lng = (const float*)d_in[21];
    const float* ag_lnb = (const float*)d_in[22];
    const float* ag_w2  = (const float*)d_in[23];
    const float* ag_b2  = (const float*)d_in[24];
    const float* fr_w1  = (const float*)d_in[25];
    const float* fr_b1  = (const float*)d_in[26];
    const float* fr_w2  = (const float*)d_in[27];
    const float* fr_b2  = (const float*)d_in[28];
    const float* alpha  = (const float*)d_in[29];
    const float* beta   = (const float*)d_in[30];
    float* out = (float*)d_out;

    // ---- workspace layout ----
    float* wsA    = (float*)d_ws;            // [8192][1536] qkv f32
    float* vol    = wsA;                     //   after attn: [8192][512] volumetric
    float* fusedF = wsA + 4194304;           //   [8192][512] fused f32
    float* Gp     = wsA + 8388608;           //   [256][1024] gate partials (1 MB)
    float* gate   = Gp + 262144;             //   [8][3]
    float* ybuf   = gate + 64;               //   [8][512]
    float* wsC    = wsA + 12582912;          // [8192][512] out_spectral f32
    float* wsD    = wsC + 4194304;           // [8192][512] out_spatial f32
    ushort* KVH   = (ushort*)(wsD + 4194304);// Kb+Vt / Hb
    ushort* Kb    = KVH;                     // [64][1024][64]
    ushort* Vt    = KVH + 4194304;           // [64][64][1024]
    ushort* Hb    = KVH;                     // [8192][1024] bf16 MLP hidden
    ushort* Bb1   = KVH + 8388608;           // [8192][512] bf16 activation buf
    ushort* Wb    = Bb1 + 4194304;           // bf16 weights (transposed)

    const dim3 blk(256);
    const dim3 g_qkv(12, 64);
    const dim3 g_d(4, 64);
    const dim3 g_2d(8, 64);
    const int g_attn = B_ * H_ * (N_ / 64);   // 1024

    // ---- weight + input conversion
    cvtw_k<<<dim3(24, 16, 8), blk, 0, stream>>>(sq_w, pq_w, sproj_w, pproj_w,
                                                vf_w1, vf_w2, fr_w1, fr_w2, Wb);
    cvt_k<false><<<2048, blk, 0, stream>>>(hsi, nullptr, Bb1);

    // ---- spectral branch
    bgemm_k<0,0,false><<<g_qkv, blk, 0, stream>>>(Bb1, Wb + WOFF_SQ, sq_b, wsA,
        M_, D3_, D_, nullptr, nullptr, nullptr, nullptr, nullptr);
    ln_k<<<M_, blk, 0, stream>>>(wsA, sq_lng, sq_lnb);
    prep_k<<<g_attn, blk, 0, stream>>>(wsA, Kb, Vt);
    fattn_k<<<g_attn, blk, 0, stream>>>(wsA, Kb, Vt, temp, Bb1);
    bgemm_k<0,0,false><<<g_d, blk, 0, stream>>>(Bb1, Wb + WOFF_SPROJ, sproj_b, wsC,
        M_, D_, D_, nullptr, nullptr, nullptr, nullptr, nullptr);

    // ---- spatial branch
    cvt_k<false><<<2048, blk, 0, stream>>>(lidar, nullptr, Bb1);
    bgemm_k<0,0,false><<<g_qkv, blk, 0, stream>>>(Bb1, Wb + WOFF_PQ, pq_b, wsA,
        M_, D3_, D_, nullptr, nullptr, nullptr, nullptr, nullptr);
    ln_k<<<M_, blk, 0, stream>>>(wsA, pq_lng, pq_lnb);
    prep_k<<<g_attn, blk, 0, stream>>>(wsA, Kb, Vt);
    fattn_k<<<g_attn, blk, 0, stream>>>(wsA, Kb, Vt, temp, Bb1);
    bgemm_k<0,0,false><<<g_d, blk, 0, stream>>>(Bb1, Wb + WOFF_PPROJ, pproj_b, wsD,
        M_, D_, D_, nullptr, nullptr, nullptr, nullptr, nullptr);

    // ---- volumetric MLP
    cvt_k<true><<<2048, blk, 0, stream>>>(wsC, wsD, Bb1);
    bgemm_k<1,1,false><<<g_2d, blk, 0, stream>>>(Bb1, Wb + WOFF_VF1, vf_b1, Hb,
        M_, 1024, D_, nullptr, nullptr, nullptr, nullptr, nullptr);
    bgemm_k<0,0,false><<<g_d, blk, 0, stream>>>(Hb, Wb + WOFF_VF2, vf_b2, vol,
        M_, D_, 1024, nullptr, nullptr, nullptr, nullptr, nullptr);

    // ---- adaptive gate (parallelized)
    means_k<<<B_ * 32, blk, 0, stream>>>(wsC, wsD, Gp);
    gate1_k<<<dim3(8, 8), blk, 0, stream>>>(Gp, ag_w1, ag_b1, ybuf);
    gate2_k<<<B_, blk, 0, stream>>>(ybuf, ag_lng, ag_lnb, ag_w2, ag_b2, gate);
    fuse_k<<<4096, blk, 0, stream>>>(wsC, wsD, vol, gate, fusedF, Bb1);

    // ---- fused recal MLP + final combine
    bgemm_k<1,1,false><<<g_2d, blk, 0, stream>>>(Bb1, Wb + WOFF_FR1, fr_b1, Hb,
        M_, 1024, D_, nullptr, nullptr, nullptr, nullptr, nullptr);
    bgemm_k<0,0,true><<<g_d, blk, 0, stream>>>(Hb, Wb + WOFF_FR2, fr_b2, out,
        M_, D_, 1024, fusedF, hsi, lidar, alpha, beta);
}

// Round 5
// 412.875 us; speedup vs baseline: 14.0329x; 1.0700x over previous
//
#include <hip/hip_runtime.h>
#include <hip/hip_bf16.h>
#include <math.h>

#define B_   8
#define N_   1024
#define D_   512
#define H_   8
#define HD_  64
#define D3_  1536
#define M_   (B_ * N_)   // 8192 tokens

// bf16 weight-pool offsets (elements)
#define WOFF_SQ    0
#define WOFF_PQ    786432
#define WOFF_SPROJ 1572864
#define WOFF_PPROJ 1835008
#define WOFF_VF1   2097152
#define WOFF_VF2   2621440
#define WOFF_FR1   3145728
#define WOFF_FR2   3670016

typedef float f32x4 __attribute__((ext_vector_type(4)));
typedef __bf16 bf16x8 __attribute__((ext_vector_type(8)));

union FragU {
    uint4 u4;
    unsigned int u[4];
    ushort s[8];
    bf16x8 v;
};

static __device__ __forceinline__ ushort f2bf(float x) {
    union { __bf16 h; ushort u; } c;
    c.h = (__bf16)x;
    return c.u;
}

static __device__ __forceinline__ unsigned int pack2(float a, float b) {
    return (unsigned int)f2bf(a) | ((unsigned int)f2bf(b) << 16);
}

static __device__ __forceinline__ float gelu_f(float x) {
    return 0.5f * x * (1.0f + erff(x * 0.7071067811865475f));
}

#if __has_builtin(__builtin_amdgcn_exp2f)
static __device__ __forceinline__ float exp2_fast(float x) { return __builtin_amdgcn_exp2f(x); }
#else
static __device__ __forceinline__ float exp2_fast(float x) { return exp2f(x); }
#endif

// async global->LDS, 16B per lane; lds base must be wave-uniform
static __device__ __forceinline__ void gload16(const ushort* g, ushort* lds) {
    __builtin_amdgcn_global_load_lds(
        (const __attribute__((address_space(1))) void*)g,
        (__attribute__((address_space(3))) void*)lds, 16, 0, 0);
}

// block-wide sum, blockDim.x == 256 (4 waves)
static __device__ __forceinline__ float blk_sum(float v, float* red) {
    #pragma unroll
    for (int off = 32; off; off >>= 1) v += __shfl_xor(v, off);
    const int w = threadIdx.x >> 6;
    __syncthreads();
    if ((threadIdx.x & 63) == 0) red[w] = v;
    __syncthreads();
    return red[0] + red[1] + red[2] + red[3];
}

// ---------------------------------------------------------------------------
// bf16 MFMA GEMM: C[M,N] = epi(A[M,K] @ W[K,N] + bias),  W given as Wt[N][K].
// 128x128 tile, BK=32, 256 thr (4 waves, 2x2), 4x4 16x16 frags per wave.
// OUT: 0 = f32 to Cv; 1 = bf16 to Cv; 2 = f32 to Cv AND bf16(v + r1) to C2.
// FINAL: C = fusedp + alpha*(acc+bias) + 0.5*beta*(r1+r2)
// ---------------------------------------------------------------------------
template <int ACT, int OUT, bool FINAL>
__global__ __launch_bounds__(256) void bgemm_k(
    const ushort* __restrict__ A, const ushort* __restrict__ Wt,
    const float* __restrict__ bias, void* __restrict__ Cv,
    ushort* __restrict__ C2, int M, int Nn, int K,
    const float* __restrict__ fusedp, const float* __restrict__ r1,
    const float* __restrict__ r2, const float* __restrict__ alphap,
    const float* __restrict__ betap)
{
    __shared__ ushort Asm[2][4096];
    __shared__ ushort Bsm[2][4096];
    const int tid = threadIdx.x;
    const int w = tid >> 6, l = tid & 63;
    const int m0 = blockIdx.y * 128, n0 = blockIdx.x * 128;
    const int wr = w >> 1, wc = w & 1;
    const int lr = l & 15, g = l >> 4;

    const int srow = (l & 15);
    const int skof = 8 * (l >> 4);

    f32x4 acc[4][4] = {};
    const int nt = K >> 5;

    const int c0 = 2 * w, c1 = 2 * w + 1;
    const int ar0 = (c0 >> 2) * 64 + (c0 & 3) * 16 + srow;
    const int ar1 = (c1 >> 2) * 64 + (c1 & 3) * 16 + srow;

    #define STAGE(buf, kt)                                                      \
        do {                                                                    \
            const int k0s = (kt) << 5;                                          \
            gload16(&A[(size_t)(m0 + ar0) * K + k0s + skof], &Asm[buf][c0*512]);\
            gload16(&A[(size_t)(m0 + ar1) * K + k0s + skof], &Asm[buf][c1*512]);\
            gload16(&Wt[(size_t)(n0 + ar0) * K + k0s + skof], &Bsm[buf][c0*512]);\
            gload16(&Wt[(size_t)(n0 + ar1) * K + k0s + skof], &Bsm[buf][c1*512]);\
        } while (0)

    STAGE(0, 0);
    __syncthreads();
    int cur = 0;
    for (int t = 0; t < nt; ++t) {
        if (t + 1 < nt) STAGE(cur ^ 1, t + 1);
        FragU af[4], bf4[4];
        #pragma unroll
        for (int mi = 0; mi < 4; ++mi)
            af[mi].u4 = *reinterpret_cast<const uint4*>(&Asm[cur][((wr*4 + mi)*64 + l)*8]);
        #pragma unroll
        for (int nj = 0; nj < 4; ++nj)
            bf4[nj].u4 = *reinterpret_cast<const uint4*>(&Bsm[cur][((wc*4 + nj)*64 + l)*8]);
        #pragma unroll
        for (int mi = 0; mi < 4; ++mi)
            #pragma unroll
            for (int nj = 0; nj < 4; ++nj)
                acc[mi][nj] = __builtin_amdgcn_mfma_f32_16x16x32_bf16(
                    af[mi].v, bf4[nj].v, acc[mi][nj], 0, 0, 0);
        __syncthreads();
        cur ^= 1;
    }
    #undef STAGE

    float alpha = 0.f, beta = 0.f;
    if (FINAL) { alpha = alphap[0]; beta = betap[0]; }
    #pragma unroll
    for (int mi = 0; mi < 4; ++mi) {
        #pragma unroll
        for (int r = 0; r < 4; ++r) {
            const int m = m0 + wr*64 + mi*16 + g*4 + r;
            #pragma unroll
            for (int nj = 0; nj < 4; ++nj) {
                const int n = n0 + wc*64 + nj*16 + lr;
                float v = acc[mi][nj][r] + bias[n];
                if (ACT == 1) v = gelu_f(v);
                if (FINAL) {
                    const size_t idx = (size_t)m * Nn + n;
                    v = fusedp[idx] + alpha * v + 0.5f * beta * (r1[idx] + r2[idx]);
                }
                const size_t idx = (size_t)m * Nn + n;
                if (OUT == 0) ((float*)Cv)[idx] = v;
                else if (OUT == 1) ((ushort*)Cv)[idx] = f2bf(v);
                else {
                    ((float*)Cv)[idx] = v;
                    C2[idx] = f2bf(v + r1[idx]);
                }
            }
        }
    }
}

// ---------------------------------------------------------------------------
// weight convert+transpose: Wt[n][k] = bf16(W[k][n]); 8 weights via blockIdx.z
// ---------------------------------------------------------------------------
__global__ __launch_bounds__(256) void cvtw_k(
    const float* __restrict__ w0, const float* __restrict__ w1,
    const float* __restrict__ w2, const float* __restrict__ w3,
    const float* __restrict__ w4, const float* __restrict__ w5,
    const float* __restrict__ w6, const float* __restrict__ w7,
    ushort* __restrict__ dst)
{
    __shared__ ushort T[64][72];
    const int id = blockIdx.z;
    int K, Nn, off;
    const float* src;
    switch (id) {
        case 0: src = w0; K = 512;  Nn = 1536; off = WOFF_SQ;    break;
        case 1: src = w1; K = 512;  Nn = 1536; off = WOFF_PQ;    break;
        case 2: src = w2; K = 512;  Nn = 512;  off = WOFF_SPROJ; break;
        case 3: src = w3; K = 512;  Nn = 512;  off = WOFF_PPROJ; break;
        case 4: src = w4; K = 512;  Nn = 1024; off = WOFF_VF1;   break;
        case 5: src = w5; K = 1024; Nn = 512;  off = WOFF_VF2;   break;
        case 6: src = w6; K = 512;  Nn = 1024; off = WOFF_FR1;   break;
        default: src = w7; K = 1024; Nn = 512; off = WOFF_FR2;   break;
    }
    const int n0 = blockIdx.x * 64, k0 = blockIdx.y * 64;
    if (n0 >= Nn || k0 >= K) return;
    const int t = threadIdx.x;
    const int q = t >> 6, e = t & 63;
    #pragma unroll 4
    for (int i = 0; i < 16; ++i) {
        const int kl = q * 16 + i;
        T[e][kl] = f2bf(src[(size_t)(k0 + kl) * Nn + n0 + e]);
    }
    __syncthreads();
    #pragma unroll 4
    for (int i = 0; i < 16; ++i) {
        const int nl = q * 16 + i;
        dst[(size_t)off + (size_t)(n0 + nl) * K + k0 + e] = T[nl][e];
    }
}

// ---------------------------------------------------------------------------
// elementwise f32 -> bf16; 8 elems/thread
// ---------------------------------------------------------------------------
__global__ __launch_bounds__(256) void cvt_k(const float* __restrict__ a,
                                             ushort* __restrict__ dst)
{
    const size_t i = ((size_t)blockIdx.x * 256 + threadIdx.x) * 8;
    const float4 x0 = *reinterpret_cast<const float4*>(a + i);
    const float4 x1 = *reinterpret_cast<const float4*>(a + i + 4);
    FragU o;
    o.u[0] = pack2(x0.x, x0.y);
    o.u[1] = pack2(x0.z, x0.w);
    o.u[2] = pack2(x1.x, x1.y);
    o.u[3] = pack2(x1.z, x1.w);
    *reinterpret_cast<uint4*>(dst + i) = o.u4;
}

// ---------------------------------------------------------------------------
// In-place row LayerNorm over 1536, float4-vectorized
// ---------------------------------------------------------------------------
__global__ __launch_bounds__(256) void ln_k(float* __restrict__ x,
                                            const float* __restrict__ g,
                                            const float* __restrict__ b)
{
    __shared__ float red[4];
    float* xr = x + (size_t)blockIdx.x * D3_;
    float s = 0.f, ss = 0.f;
    for (int j = threadIdx.x * 4; j < D3_; j += 1024) {
        const float4 v = *reinterpret_cast<const float4*>(xr + j);
        s += v.x + v.y + v.z + v.w;
        ss += v.x*v.x + v.y*v.y + v.z*v.z + v.w*v.w;
    }
    s = blk_sum(s, red);
    ss = blk_sum(ss, red);
    const float mu = s * (1.0f / D3_);
    const float var = ss * (1.0f / D3_) - mu * mu;
    const float rs = rsqrtf(var + 1e-5f);
    for (int j = threadIdx.x * 4; j < D3_; j += 1024) {
        float4 v = *reinterpret_cast<const float4*>(xr + j);
        const float4 gv = *reinterpret_cast<const float4*>(g + j);
        const float4 bv = *reinterpret_cast<const float4*>(b + j);
        v.x = (v.x - mu) * rs * gv.x + bv.x;
        v.y = (v.y - mu) * rs * gv.y + bv.y;
        v.z = (v.z - mu) * rs * gv.z + bv.z;
        v.w = (v.w - mu) * rs * gv.w + bv.w;
        *reinterpret_cast<float4*>(xr + j) = v;
    }
}

// ---------------------------------------------------------------------------
// prep: l2norm K -> bf16 Kb[bh][n][64]; V -> bf16 transposed Vt[bh][d][1024]
// ---------------------------------------------------------------------------
__global__ __launch_bounds__(256) void prep_k(const float* __restrict__ qkv,
                                              ushort* __restrict__ Kb,
                                              ushort* __restrict__ Vt)
{
    __shared__ ushort Vs[64 * 72];
    const int nb = blockIdx.x & 15;
    const int h  = (blockIdx.x >> 4) & 7;
    const int b  = blockIdx.x >> 7;
    const int bh = b * 8 + h;
    const int n0 = nb * 64;
    const int w = threadIdx.x >> 6;
    const int l = threadIdx.x & 63;

    #pragma unroll 4
    for (int i = 0; i < 16; ++i) {
        const int row = w * 16 + i;
        const float* base = qkv + ((size_t)(b * N_) + n0 + row) * D3_ + h * HD_;
        const float kvl = base[D_ + l];
        const float vvl = base[2 * D_ + l];
        float ssq = kvl * kvl;
        #pragma unroll
        for (int off = 32; off; off >>= 1) ssq += __shfl_xor(ssq, off);
        const float sc = 1.0f / fmaxf(sqrtf(ssq), 1e-12f);
        Kb[((size_t)bh * N_ + n0 + row) * HD_ + l] = f2bf(kvl * sc);
        Vs[row * 72 + l] = f2bf(vvl);
    }
    __syncthreads();
    const int d = threadIdx.x >> 2, seg = threadIdx.x & 3;
    ushort tmp[16];
    #pragma unroll
    for (int i = 0; i < 16; ++i) tmp[i] = Vs[(seg * 16 + i) * 72 + d];
    ushort* dst = Vt + ((size_t)bh * HD_ + d) * N_ + n0 + seg * 16;
    *reinterpret_cast<uint4*>(dst)     = *reinterpret_cast<uint4*>(&tmp[0]);
    *reinterpret_cast<uint4*>(dst + 8) = *reinterpret_cast<uint4*>(&tmp[8]);
}

// ---------------------------------------------------------------------------
// Flash-style cosine attention, bf16 MFMA, swapped QK^T.
// QBLK=128 (4 waves x 32 q-rows), KVBLK=64, grid 512, XCD-swizzled.
// Async-split K/V staging (load regs early, ds_write after barrier).
// exp2-domain softmax: scores scaled by log2e, static shift m = |t|*log2e.
// ---------------------------------------------------------------------------
__global__ __launch_bounds__(256) void fattn_k(const float* __restrict__ qkv,
                                               const ushort* __restrict__ Kb,
                                               const ushort* __restrict__ Vt,
                                               const float* __restrict__ temp,
                                               ushort* __restrict__ out)
{
    __shared__ ushort Ks[64 * 72];
    __shared__ ushort Vs[64 * 72];
    const int tid = threadIdx.x;
    // XCD swizzle (512 blocks, 8 XCDs): 64 consecutive logical wg per XCD
    const int wg = ((blockIdx.x & 7) << 6) | (blockIdx.x >> 3);
    const int nb = wg & 7;
    const int h  = (wg >> 3) & 7;
    const int b  = wg >> 6;
    const int bh = b * 8 + h;
    const int n0 = nb * 128;
    const int w  = tid >> 6;
    const int l  = tid & 63;
    const int lr = l & 15;
    const int g  = l >> 4;
    const float t = temp[h];
    const float L2E = 1.4426950408889634f;
    const float m2 = fabsf(t) * L2E;

    // ---- Q fragments: two 16-row groups per wave (rows qb+lr, qb+16+lr)
    const int qb = n0 + w * 32;
    FragU qa0, qa1, qb0, qb1;
    #pragma unroll
    for (int grp = 0; grp < 2; ++grp) {
        const float* qrow = qkv + ((size_t)(b * N_) + qb + grp * 16 + lr) * D3_ + h * HD_;
        float qv[16];
        const float4 q0 = *reinterpret_cast<const float4*>(qrow + 8 * g);
        const float4 q1 = *reinterpret_cast<const float4*>(qrow + 8 * g + 4);
        const float4 q2 = *reinterpret_cast<const float4*>(qrow + 32 + 8 * g);
        const float4 q3 = *reinterpret_cast<const float4*>(qrow + 32 + 8 * g + 4);
        qv[0]=q0.x; qv[1]=q0.y; qv[2]=q0.z; qv[3]=q0.w;
        qv[4]=q1.x; qv[5]=q1.y; qv[6]=q1.z; qv[7]=q1.w;
        qv[8]=q2.x; qv[9]=q2.y; qv[10]=q2.z; qv[11]=q2.w;
        qv[12]=q3.x; qv[13]=q3.y; qv[14]=q3.z; qv[15]=q3.w;
        float ssq = 0.f;
        #pragma unroll
        for (int e = 0; e < 16; ++e) ssq += qv[e] * qv[e];
        ssq += __shfl_xor(ssq, 16);
        ssq += __shfl_xor(ssq, 32);
        const float qs = (t * L2E) / fmaxf(sqrtf(ssq), 1e-12f);
        FragU f0, f1;
        #pragma unroll
        for (int e = 0; e < 8; ++e) {
            f0.s[e] = f2bf(qv[e] * qs);
            f1.s[e] = f2bf(qv[8 + e] * qs);
        }
        if (grp == 0) { qa0 = f0; qa1 = f1; }
        else          { qb0 = f0; qb1 = f1; }
    }

    f32x4 OA[4] = {};
    f32x4 OB[4] = {};
    float lsA = 0.f, lsB = 0.f;

    const ushort* kbase = Kb + (size_t)bh * N_ * HD_;
    const ushort* vbase = Vt + (size_t)bh * HD_ * N_;
    const int sr = tid >> 3;          // 0..31
    const int sc = (tid & 7) * 8;     // ushort offset, 16B chunks
    uint4 k0r, k1r, v0r, v1r;

    #define LOADT(kt)                                                           \
        do {                                                                    \
            const ushort* ks_ = kbase + (size_t)((kt) * 64) * HD_;              \
            const ushort* vs_ = vbase + (kt) * 64;                              \
            k0r = *reinterpret_cast<const uint4*>(ks_ + sr * HD_ + sc);         \
            k1r = *reinterpret_cast<const uint4*>(ks_ + (sr + 32) * HD_ + sc);  \
            v0r = *reinterpret_cast<const uint4*>(vs_ + (size_t)sr * N_ + sc);  \
            v1r = *reinterpret_cast<const uint4*>(vs_ + (size_t)(sr + 32) * N_ + sc); \
        } while (0)
    #define WRITET()                                                            \
        do {                                                                    \
            *reinterpret_cast<uint4*>(&Ks[sr * 72 + sc]) = k0r;                 \
            *reinterpret_cast<uint4*>(&Ks[(sr + 32) * 72 + sc]) = k1r;          \
            *reinterpret_cast<uint4*>(&Vs[sr * 72 + sc]) = v0r;                 \
            *reinterpret_cast<uint4*>(&Vs[(sr + 32) * 72 + sc]) = v1r;          \
        } while (0)

    LOADT(0);
    WRITET();
    __syncthreads();

    #pragma unroll 1
    for (int kt = 0; kt < 16; ++kt) {
        if (kt < 15) LOADT(kt + 1);   // issue early; waits at WRITET after compute

        // ---- QK^T (swapped): per j-subtile, K-frags shared by both q-groups
        unsigned paA[2][4], paB[2][4];
        #pragma unroll
        for (int j = 0; j < 4; ++j) {
            FragU ka, kc;
            ka.u4 = *reinterpret_cast<const uint4*>(&Ks[(j * 16 + lr) * 72 + 8 * g]);
            kc.u4 = *reinterpret_cast<const uint4*>(&Ks[(j * 16 + lr) * 72 + 32 + 8 * g]);
            f32x4 sA = {0.f,0.f,0.f,0.f}, sB = {0.f,0.f,0.f,0.f};
            sA = __builtin_amdgcn_mfma_f32_16x16x32_bf16(ka.v, qa0.v, sA, 0, 0, 0);
            sA = __builtin_amdgcn_mfma_f32_16x16x32_bf16(kc.v, qa1.v, sA, 0, 0, 0);
            sB = __builtin_amdgcn_mfma_f32_16x16x32_bf16(ka.v, qb0.v, sB, 0, 0, 0);
            sB = __builtin_amdgcn_mfma_f32_16x16x32_bf16(kc.v, qb1.v, sB, 0, 0, 0);
            float pA[4], pB[4];
            #pragma unroll
            for (int r = 0; r < 4; ++r) {
                pA[r] = exp2_fast(sA[r] - m2);
                pB[r] = exp2_fast(sB[r] - m2);
                lsA += pA[r];
                lsB += pB[r];
            }
            paA[j >> 1][2 * (j & 1) + 0] = pack2(pA[0], pA[1]);
            paA[j >> 1][2 * (j & 1) + 1] = pack2(pA[2], pA[3]);
            paB[j >> 1][2 * (j & 1) + 0] = pack2(pB[0], pB[1]);
            paB[j >> 1][2 * (j & 1) + 1] = pack2(pB[2], pB[3]);
        }

        // ---- PV: V-frags shared by both q-groups
        #pragma unroll
        for (int ks = 0; ks < 2; ++ks) {
            FragU fa, fb2;
            fa.u[0] = paA[ks][0]; fa.u[1] = paA[ks][1];
            fa.u[2] = paA[ks][2]; fa.u[3] = paA[ks][3];
            fb2.u[0] = paB[ks][0]; fb2.u[1] = paB[ks][1];
            fb2.u[2] = paB[ks][2]; fb2.u[3] = paB[ks][3];
            #pragma unroll
            for (int s4 = 0; s4 < 4; ++s4) {
                FragU vb;
                const int vi = (lr + 16 * s4) * 72 + ks * 32 + 4 * g;
                *reinterpret_cast<uint2*>(&vb.u[0]) =
                    *reinterpret_cast<const uint2*>(&Vs[vi]);
                *reinterpret_cast<uint2*>(&vb.u[2]) =
                    *reinterpret_cast<const uint2*>(&Vs[vi + 16]);
                OA[s4] = __builtin_amdgcn_mfma_f32_16x16x32_bf16(fa.v, vb.v, OA[s4], 0, 0, 0);
                OB[s4] = __builtin_amdgcn_mfma_f32_16x16x32_bf16(fb2.v, vb.v, OB[s4], 0, 0, 0);
            }
        }

        if (kt < 15) {
            __syncthreads();
            WRITET();
            __syncthreads();
        }
    }
    #undef LOADT
    #undef WRITET

    // ---- normalize and store (bf16)
    lsA += __shfl_xor(lsA, 16); lsA += __shfl_xor(lsA, 32);
    lsB += __shfl_xor(lsB, 16); lsB += __shfl_xor(lsB, 32);
    const float invA = 1.0f / lsA;
    const float invB = 1.0f / lsB;
    ushort* outp = out + ((size_t)(b * N_) + qb) * D_ + h * HD_;
    #pragma unroll
    for (int r = 0; r < 4; ++r) {
        const float iA = __shfl(invA, 4 * g + r);
        const float iB = __shfl(invB, 4 * g + r);
        ushort* rowA = outp + (size_t)(4 * g + r) * D_;
        ushort* rowB = outp + (size_t)(16 + 4 * g + r) * D_;
        #pragma unroll
        for (int s4 = 0; s4 < 4; ++s4) {
            rowA[s4 * 16 + lr] = f2bf(OA[s4][r] * iA);
            rowB[s4 * 16 + lr] = f2bf(OB[s4][r] * iB);
        }
    }
}

// ---------------------------------------------------------------------------
// Partial column sums for gate means: 32-row chunks, grid = B*32 = 256 blocks
// ---------------------------------------------------------------------------
__global__ __launch_bounds__(256) void means_k(const float* __restrict__ spec,
                                               const float* __restrict__ spat,
                                               float* __restrict__ Gp)
{
    const int b = blockIdx.x >> 5;
    const int ch = blockIdx.x & 31;
    const int n0 = ch * 32;
    for (int d = threadIdx.x; d < D_; d += 256) {
        float s1 = 0.f, s2 = 0.f;
        #pragma unroll 4
        for (int n = 0; n < 32; ++n) {
            const size_t idx = ((size_t)(b * N_) + n0 + n) * D_ + d;
            s1 += spec[idx];
            s2 += spat[idx];
        }
        Gp[(size_t)blockIdx.x * 1024 + d] = s1;
        Gp[(size_t)blockIdx.x * 1024 + 512 + d] = s2;
    }
}

// ---------------------------------------------------------------------------
// gate GEMV: y[b][512] = mean-vec(xs) @ ag_w1 + b1. grid (8 jc, 8 b).
// ---------------------------------------------------------------------------
__global__ __launch_bounds__(256) void gate1_k(const float* __restrict__ Gp,
                                               const float* __restrict__ w1,
                                               const float* __restrict__ b1,
                                               float* __restrict__ y)
{
    __shared__ float xs[1024];
    __shared__ float red[4][64];
    const int jc = blockIdx.x, b = blockIdx.y, tid = threadIdx.x;
    for (int k = tid; k < 1024; k += 256) {
        float s = 0.f;
        #pragma unroll 8
        for (int c = 0; c < 32; ++c) s += Gp[(size_t)(b * 32 + c) * 1024 + k];
        xs[k] = s * (1.0f / N_);
    }
    __syncthreads();
    const int jl = tid & 63;
    const int jj = jc * 64 + jl;
    const int seg = tid >> 6;
    float acc = 0.f;
    const float* wp = w1 + (size_t)(seg * 256) * 512 + jj;
    const float* xp = xs + seg * 256;
    #pragma unroll 8
    for (int k = 0; k < 256; ++k) acc += xp[k] * wp[(size_t)k * 512];
    red[seg][jl] = acc;
    __syncthreads();
    if (tid < 64)
        y[b * 512 + jc * 64 + tid] =
            red[0][tid] + red[1][tid] + red[2][tid] + red[3][tid] + b1[jc * 64 + tid];
}

// ---------------------------------------------------------------------------
// gate tail: LN(512) -> GELU -> @ag_w2[512,3]+b2 -> softmax. grid = 8 blocks.
// ---------------------------------------------------------------------------
__global__ __launch_bounds__(256) void gate2_k(const float* __restrict__ y,
                                               const float* __restrict__ lng,
                                               const float* __restrict__ lnb,
                                               const float* __restrict__ w2,
                                               const float* __restrict__ b2,
                                               float* __restrict__ gate)
{
    __shared__ float red[4];
    const int b = blockIdx.x, tid = threadIdx.x;
    const float v0 = y[b * 512 + tid];
    const float v1 = y[b * 512 + 256 + tid];
    const float s = blk_sum(v0 + v1, red);
    const float ss = blk_sum(v0 * v0 + v1 * v1, red);
    const float mu = s * (1.0f / 512.0f);
    const float var = ss * (1.0f / 512.0f) - mu * mu;
    const float rs = rsqrtf(var + 1e-5f);
    const float z0 = gelu_f((v0 - mu) * rs * lng[tid] + lnb[tid]);
    const float z1 = gelu_f((v1 - mu) * rs * lng[tid + 256] + lnb[tid + 256]);
    float p0 = z0 * w2[tid * 3 + 0] + z1 * w2[(tid + 256) * 3 + 0];
    float p1 = z0 * w2[tid * 3 + 1] + z1 * w2[(tid + 256) * 3 + 1];
    float p2 = z0 * w2[tid * 3 + 2] + z1 * w2[(tid + 256) * 3 + 2];
    p0 = blk_sum(p0, red);
    p1 = blk_sum(p1, red);
    p2 = blk_sum(p2, red);
    if (tid == 0) {
        p0 += b2[0]; p1 += b2[1]; p2 += b2[2];
        const float m = fmaxf(p0, fmaxf(p1, p2));
        const float e0 = expf(p0 - m), e1 = expf(p1 - m), e2 = expf(p2 - m);
        const float inv = 1.0f / (e0 + e1 + e2);
        gate[b * 3 + 0] = e0 * inv;
        gate[b * 3 + 1] = e1 * inv;
        gate[b * 3 + 2] = e2 * inv;
    }
}

// ---------------------------------------------------------------------------
// fused = g0*spec + g1*spat + g2*vol; writes f32 AND bf16 copies
// ---------------------------------------------------------------------------
__global__ __launch_bounds__(256) void fuse_k(
    const float* __restrict__ spec, const float* __restrict__ spat,
    const float* __restrict__ vol, const float* __restrict__ gate,
    float* __restrict__ fusedF, ushort* __restrict__ fb)
{
    const size_t i4 = ((size_t)blockIdx.x * 256 + threadIdx.x) * 4;
    const int b = (int)(i4 >> 19);
    const float g0 = gate[b * 3 + 0], g1 = gate[b * 3 + 1], g2 = gate[b * 3 + 2];
    const float4 a = *reinterpret_cast<const float4*>(spec + i4);
    const float4 c = *reinterpret_cast<const float4*>(spat + i4);
    const float4 v = *reinterpret_cast<const float4*>(vol + i4);
    float4 o;
    o.x = g0 * a.x + g1 * c.x + g2 * v.x;
    o.y = g0 * a.y + g1 * c.y + g2 * v.y;
    o.z = g0 * a.z + g1 * c.z + g2 * v.z;
    o.w = g0 * a.w + g1 * c.w + g2 * v.w;
    *reinterpret_cast<float4*>(fusedF + i4) = o;
    union { ushort s[4]; uint2 u; } ob;
    ob.s[0] = f2bf(o.x); ob.s[1] = f2bf(o.y);
    ob.s[2] = f2bf(o.z); ob.s[3] = f2bf(o.w);
    *reinterpret_cast<uint2*>(fb + i4) = ob.u;
}

// ---------------------------------------------------------------------------
extern "C" void kernel_launch(void* const* d_in, const int* in_sizes, int n_in,
                              void* d_out, int out_size, void* d_ws, size_t ws_size,
                              hipStream_t stream)
{
    const float* hsi    = (const float*)d_in[0];
    const float* lidar  = (const float*)d_in[1];
    const float* temp   = (const float*)d_in[2];
    const float* sq_w   = (const float*)d_in[3];
    const float* sq_b   = (const float*)d_in[4];
    const float* sq_lng = (const float*)d_in[5];
    const float* sq_lnb = (const float*)d_in[6];
    const float* sproj_w = (const float*)d_in[7];
    const float* sproj_b = (const float*)d_in[8];
    const float* pq_w   = (const float*)d_in[9];
    const float* pq_b   = (const float*)d_in[10];
    const float* pq_lng = (const float*)d_in[11];
    const float* pq_lnb = (const float*)d_in[12];
    const float* pproj_w = (const float*)d_in[13];
    const float* pproj_b = (const float*)d_in[14];
    const float* vf_w1  = (const float*)d_in[15];
    const float* vf_b1  = (const float*)d_in[16];
    const float* vf_w2  = (const float*)d_in[17];
    const float* vf_b2  = (const float*)d_in[18];
    const float* ag_w1  = (const float*)d_in[19];
    const float* ag_b1  = (const float*)d_in[20];
    const float* ag_lng = (const float*)d_in[21];
    const float* ag_lnb = (const float*)d_in[22];
    const float* ag_w2  = (const float*)d_in[23];
    const float* ag_b2  = (const float*)d_in[24];
    const float* fr_w1  = (const float*)d_in[25];
    const float* fr_b1  = (const float*)d_in[26];
    const float* fr_w2  = (const float*)d_in[27];
    const float* fr_b2  = (const float*)d_in[28];
    const float* alpha  = (const float*)d_in[29];
    const float* beta   = (const float*)d_in[30];
    float* out = (float*)d_out;

    // ---- workspace layout ----
    float* wsA    = (float*)d_ws;            // [8192][1536] qkv f32
    float* vol    = wsA;                     //   later: [8192][512] volumetric f32
    ushort* Sb    = (ushort*)wsA;            //   later: [8192][512] bf16 spec+spat
    float* fusedF = wsA + 4194304;           //   [8192][512] fused f32
    float* Gp     = wsA + 8388608;           //   [256][1024] gate partials
    float* gate   = Gp + 262144;             //   [8][3]
    float* ybuf   = gate + 64;               //   [8][512]
    float* wsC    = wsA + 12582912;          // [8192][512] out_spectral f32
    float* wsD    = wsC + 4194304;           // [8192][512] out_spatial f32
    ushort* KVH   = (ushort*)(wsD + 4194304);// Kb+Vt / Hb (16.78 MB)
    ushort* Kb    = KVH;                     // [64][1024][64]
    ushort* Vt    = KVH + 4194304;           // [64][64][1024]
    ushort* Hb    = KVH;                     // [8192][1024] bf16 MLP hidden
    ushort* Bb1   = KVH + 8388608;           // [8192][512] bf16 activation buf
    ushort* Wb    = Bb1 + 4194304;           // bf16 weights (transposed)

    const dim3 blk(256);
    const dim3 g_qkv(12, 64);
    const dim3 g_d(4, 64);
    const dim3 g_2d(8, 64);
    const int g_prep = B_ * H_ * (N_ / 64);    // 1024
    const int g_attn = B_ * H_ * (N_ / 128);   // 512

    // ---- weight + input conversion
    cvtw_k<<<dim3(24, 16, 8), blk, 0, stream>>>(sq_w, pq_w, sproj_w, pproj_w,
                                                vf_w1, vf_w2, fr_w1, fr_w2, Wb);
    cvt_k<<<2048, blk, 0, stream>>>(hsi, Bb1);

    // ---- spectral branch
    bgemm_k<0,0,false><<<g_qkv, blk, 0, stream>>>(Bb1, Wb + WOFF_SQ, sq_b, wsA, nullptr,
        M_, D3_, D_, nullptr, nullptr, nullptr, nullptr, nullptr);
    ln_k<<<M_, blk, 0, stream>>>(wsA, sq_lng, sq_lnb);
    prep_k<<<g_prep, blk, 0, stream>>>(wsA, Kb, Vt);
    fattn_k<<<g_attn, blk, 0, stream>>>(wsA, Kb, Vt, temp, Bb1);
    bgemm_k<0,0,false><<<g_d, blk, 0, stream>>>(Bb1, Wb + WOFF_SPROJ, sproj_b, wsC, nullptr,
        M_, D_, D_, nullptr, nullptr, nullptr, nullptr, nullptr);

    // ---- spatial branch
    cvt_k<<<2048, blk, 0, stream>>>(lidar, Bb1);
    bgemm_k<0,0,false><<<g_qkv, blk, 0, stream>>>(Bb1, Wb + WOFF_PQ, pq_b, wsA, nullptr,
        M_, D3_, D_, nullptr, nullptr, nullptr, nullptr, nullptr);
    ln_k<<<M_, blk, 0, stream>>>(wsA, pq_lng, pq_lnb);
    prep_k<<<g_prep, blk, 0, stream>>>(wsA, Kb, Vt);
    fattn_k<<<g_attn, blk, 0, stream>>>(wsA, Kb, Vt, temp, Bb1);
    // pproj: wsD f32 AND Sb = bf16(spat + spec)  (spec = wsC, r1)
    bgemm_k<0,2,false><<<g_d, blk, 0, stream>>>(Bb1, Wb + WOFF_PPROJ, pproj_b, wsD, Sb,
        M_, D_, D_, nullptr, wsC, nullptr, nullptr, nullptr);

    // ---- adaptive gate (only needs wsC/wsD)
    means_k<<<B_ * 32, blk, 0, stream>>>(wsC, wsD, Gp);
    gate1_k<<<dim3(8, 8), blk, 0, stream>>>(Gp, ag_w1, ag_b1, ybuf);
    gate2_k<<<B_, blk, 0, stream>>>(ybuf, ag_lng, ag_lnb, ag_w2, ag_b2, gate);

    // ---- volumetric MLP: Hb = gelu(Sb@vf_w1+b1); vol = Hb@vf_w2+b2
    bgemm_k<1,1,false><<<g_2d, blk, 0, stream>>>(Sb, Wb + WOFF_VF1, vf_b1, Hb, nullptr,
        M_, 1024, D_, nullptr, nullptr, nullptr, nullptr, nullptr);
    bgemm_k<0,0,false><<<g_d, blk, 0, stream>>>(Hb, Wb + WOFF_VF2, vf_b2, vol, nullptr,
        M_, D_, 1024, nullptr, nullptr, nullptr, nullptr, nullptr);

    // ---- fuse + recal MLP + final combine
    fuse_k<<<4096, blk, 0, stream>>>(wsC, wsD, vol, gate, fusedF, Bb1);
    bgemm_k<1,1,false><<<g_2d, blk, 0, stream>>>(Bb1, Wb + WOFF_FR1, fr_b1, Hb, nullptr,
        M_, 1024, D_, nullptr, nullptr, nullptr, nullptr, nullptr);
    bgemm_k<0,0,true><<<g_d, blk, 0, stream>>>(Hb, Wb + WOFF_FR2, fr_b2, out, nullptr,
        M_, D_, 1024, fusedF, hsi, lidar, alpha, beta);
}